// Round 1
// baseline (1452.375 us; speedup 1.0000x reference)
//
#include <hip/hip_runtime.h>

#define NN 100000
#define NE 600000
#define CC 128
#define NCHUNKS 49           // ceil(NN / 2048)
#define WT_STRIDE 132

// ---------------- CSR build ----------------

__global__ void k_zero(int* __restrict__ p, int n) {
    int i = blockIdx.x * blockDim.x + threadIdx.x;
    if (i < n) p[i] = 0;
}

__global__ void k_hist(const int* __restrict__ ei, int* __restrict__ cnt) {
    int e = blockIdx.x * blockDim.x + threadIdx.x;
    if (e < NE) atomicAdd(&cnt[ei[NE + e]], 1);
}

// chunk = 2048 elems, 256 thr x 8
__global__ void k_scan1(const int* __restrict__ deg, int* __restrict__ csum) {
    __shared__ int s[256];
    int c = blockIdx.x, t = threadIdx.x;
    int base = c * 2048 + t * 8;
    int v = 0;
#pragma unroll
    for (int u = 0; u < 8; ++u) { int i = base + u; if (i < NN) v += deg[i]; }
    s[t] = v; __syncthreads();
    for (int off = 128; off > 0; off >>= 1) {
        if (t < off) s[t] += s[t + off];
        __syncthreads();
    }
    if (t == 0) csum[c] = s[0];
}

__global__ void k_scan2(int* __restrict__ csum_ui, int* __restrict__ csum_iu,
                        int* __restrict__ rp_ui, int* __restrict__ rp_iu) {
    int* cs = blockIdx.x ? csum_iu : csum_ui;
    int* rp = blockIdx.x ? rp_iu : rp_ui;
    int run = 0;
    for (int i = 0; i < NCHUNKS; ++i) { int v = cs[i]; cs[i] = run; run += v; }
    rp[NN] = run;
}

__global__ void k_scan3(const int* __restrict__ csum, int* __restrict__ degcur,
                        int* __restrict__ rp) {
    __shared__ int s[256];
    int c = blockIdx.x, t = threadIdx.x;
    int base = c * 2048 + t * 8;
    int loc[8]; int v = 0;
#pragma unroll
    for (int u = 0; u < 8; ++u) { int i = base + u; loc[u] = (i < NN) ? degcur[i] : 0; v += loc[u]; }
    s[t] = v; __syncthreads();
    for (int off = 1; off < 256; off <<= 1) {
        int x = (t >= off) ? s[t - off] : 0;
        __syncthreads();
        s[t] += x;
        __syncthreads();
    }
    int pre = s[t] - v + csum[c];
#pragma unroll
    for (int u = 0; u < 8; ++u) {
        int i = base + u;
        if (i < NN) { rp[i] = pre; degcur[i] = pre; pre += loc[u]; }
    }
}

__global__ void k_fill(const int* __restrict__ ei, int* __restrict__ cur,
                       int* __restrict__ csr) {
    int e = blockIdx.x * blockDim.x + threadIdx.x;
    if (e < NE) {
        int src = ei[e], dst = ei[NE + e];
        int pos = atomicAdd(&cur[dst], 1);
        csr[pos] = src;
    }
}

// ---------------- aggregation: mean of neighbor rows ----------------

__global__ __launch_bounds__(128)
void k_agg(const float* __restrict__ xsrc, const int* __restrict__ rp,
           const int* __restrict__ csr, float* __restrict__ mean) {
    int d = blockIdx.x;
    int j = threadIdx.x;
    int b = rp[d], e = rp[d + 1];
    float acc = 0.f;
    for (int i = b; i < e; ++i) {
        int s = csr[i];
        acc += xsrc[(size_t)s * CC + j];
    }
    int deg = e - b;
    float inv = 1.f / (float)(deg > 1 ? deg : 1);
    mean[(size_t)d * CC + j] = acc * inv;
}

// ---------------- fused [mean|x] @ W^T + b -> LN -> ReLU ----------------
// 512 threads = 16 nodes per iter, 32 lanes per node, 4 outputs per lane.
// W^T staged in LDS with stride 132 (16B-aligned rows, conflict-free b128 reads).

__global__ __launch_bounds__(512)
void k_gemm_ln(const float* __restrict__ mean, const float* __restrict__ xdst,
               const float* __restrict__ Wl, const float* __restrict__ bl,
               const float* __restrict__ Wr, const float* __restrict__ g,
               const float* __restrict__ bb, float* __restrict__ out) {
    __shared__ float WT[256 * WT_STRIDE];          // 135168 B
    __shared__ float rows[16][256];                // 16384 B
    __shared__ float sbl[128], sg[128], sb[128];   // 1536 B

    int t = threadIdx.x;
    // stage W transposed: thread t handles row jj = t%128, k-range [kq*64, kq*64+64)
    {
        int jj = t & 127, kq = t >> 7;
        const float* wlr = Wl + (size_t)jj * CC;
        const float* wrr = Wr + (size_t)jj * CC;
#pragma unroll
        for (int u = 0; u < 16; ++u) {
            int k = kq * 64 + u * 4;
            float4 w;
            if (k < 128) w = *reinterpret_cast<const float4*>(wlr + k);
            else         w = *reinterpret_cast<const float4*>(wrr + (k - 128));
            WT[(k + 0) * WT_STRIDE + jj] = w.x;
            WT[(k + 1) * WT_STRIDE + jj] = w.y;
            WT[(k + 2) * WT_STRIDE + jj] = w.z;
            WT[(k + 3) * WT_STRIDE + jj] = w.w;
        }
        if (t < 128) { sbl[t] = bl[t]; sg[t] = g[t]; sb[t] = bb[t]; }
    }
    __syncthreads();

    int nloc = t >> 5;        // 0..15
    int jl = t & 31;          // 0..31
    int j0 = jl * 4;

    for (int base = blockIdx.x * 16; base < NN; base += gridDim.x * 16) {
        int node = base + nloc;
        bool valid = node < NN;
        if (valid) {
            float4 m4 = *reinterpret_cast<const float4*>(mean + (size_t)node * CC + j0);
            float4 x4 = *reinterpret_cast<const float4*>(xdst + (size_t)node * CC + j0);
            *reinterpret_cast<float4*>(&rows[nloc][j0]) = m4;
            *reinterpret_cast<float4*>(&rows[nloc][128 + j0]) = x4;
        }
        __syncthreads();

        float4 acc = make_float4(sbl[j0], sbl[j0 + 1], sbl[j0 + 2], sbl[j0 + 3]);
        const float* rowp = rows[nloc];
#pragma unroll 8
        for (int k = 0; k < 256; ++k) {
            float rv = rowp[k];
            float4 w = *reinterpret_cast<const float4*>(&WT[k * WT_STRIDE + j0]);
            acc.x = fmaf(rv, w.x, acc.x);
            acc.y = fmaf(rv, w.y, acc.y);
            acc.z = fmaf(rv, w.z, acc.z);
            acc.w = fmaf(rv, w.w, acc.w);
        }

        // LayerNorm over the node's 128 outputs (held by 32 lanes x 4)
        float s1 = acc.x + acc.y + acc.z + acc.w;
        float s2 = acc.x * acc.x + acc.y * acc.y + acc.z * acc.z + acc.w * acc.w;
#pragma unroll
        for (int m = 1; m < 32; m <<= 1) {
            s1 += __shfl_xor(s1, m);
            s2 += __shfl_xor(s2, m);
        }
        float mu = s1 * (1.f / 128.f);
        float var = s2 * (1.f / 128.f) - mu * mu;
        float rstd = rsqrtf(var + 1e-5f);
        float4 o;
        o.x = fmaxf(0.f, (acc.x - mu) * rstd * sg[j0 + 0] + sb[j0 + 0]);
        o.y = fmaxf(0.f, (acc.y - mu) * rstd * sg[j0 + 1] + sb[j0 + 1]);
        o.z = fmaxf(0.f, (acc.z - mu) * rstd * sg[j0 + 2] + sb[j0 + 2]);
        o.w = fmaxf(0.f, (acc.w - mu) * rstd * sg[j0 + 3] + sb[j0 + 3]);
        if (valid) *reinterpret_cast<float4*>(out + (size_t)node * CC + j0) = o;
        __syncthreads();
    }
}

// ---------------- launch ----------------

extern "C" void kernel_launch(void* const* d_in, const int* in_sizes, int n_in,
                              void* d_out, int out_size, void* d_ws, size_t ws_size,
                              hipStream_t stream) {
    const float* x_user = (const float*)d_in[0];
    const float* x_item = (const float*)d_in[1];
    const int* ei_ui = (const int*)d_in[2];
    const int* ei_iu = (const int*)d_in[3];

    const float* Wl_ui[2] = {(const float*)d_in[4],  (const float*)d_in[14]};
    const float* bl_ui[2] = {(const float*)d_in[5],  (const float*)d_in[15]};
    const float* Wr_ui[2] = {(const float*)d_in[6],  (const float*)d_in[16]};
    const float* Wl_iu[2] = {(const float*)d_in[7],  (const float*)d_in[17]};
    const float* bl_iu[2] = {(const float*)d_in[8],  (const float*)d_in[18]};
    const float* Wr_iu[2] = {(const float*)d_in[9],  (const float*)d_in[19]};
    const float* g_user[2] = {(const float*)d_in[10], (const float*)d_in[20]};
    const float* b_user[2] = {(const float*)d_in[11], (const float*)d_in[21]};
    const float* g_item[2] = {(const float*)d_in[12], (const float*)d_in[22]};
    const float* b_item[2] = {(const float*)d_in[13], (const float*)d_in[23]};

    // workspace carve (256B aligned regions)
    auto align = [](size_t x) { return (x + 255) & ~(size_t)255; };
    char* w = (char*)d_ws;
    int* cur_ui = (int*)w;                       // NN   (also deg, then fill cursor)
    int* cur_iu = cur_ui + NN;                   // NN   (contiguous with cur_ui for zeroing)
    w += align((size_t)2 * NN * 4);
    int* csum_ui = (int*)w; w += align(64 * 4);
    int* csum_iu = (int*)w; w += align(64 * 4);
    int* rp_ui = (int*)w; w += align((size_t)(NN + 1) * 4);
    int* rp_iu = (int*)w; w += align((size_t)(NN + 1) * 4);
    int* csr_ui = (int*)w; w += align((size_t)NE * 4);
    int* csr_iu = (int*)w; w += align((size_t)NE * 4);
    float* mean_item = (float*)w; w += align((size_t)NN * CC * 4);
    float* mean_user = (float*)w; w += align((size_t)NN * CC * 4);

    float* out_user = (float*)d_out;
    float* out_item = (float*)d_out + (size_t)NN * CC;

    int hb = (NE + 255) / 256;

    // ---- CSR build (shared by both layers) ----
    k_zero<<<(2 * NN + 255) / 256, 256, 0, stream>>>(cur_ui, 2 * NN);
    k_hist<<<hb, 256, 0, stream>>>(ei_ui, cur_ui);
    k_hist<<<hb, 256, 0, stream>>>(ei_iu, cur_iu);
    k_scan1<<<NCHUNKS, 256, 0, stream>>>(cur_ui, csum_ui);
    k_scan1<<<NCHUNKS, 256, 0, stream>>>(cur_iu, csum_iu);
    k_scan2<<<2, 1, 0, stream>>>(csum_ui, csum_iu, rp_ui, rp_iu);
    k_scan3<<<NCHUNKS, 256, 0, stream>>>(csum_ui, cur_ui, rp_ui);
    k_scan3<<<NCHUNKS, 256, 0, stream>>>(csum_iu, cur_iu, rp_iu);
    k_fill<<<hb, 256, 0, stream>>>(ei_ui, cur_ui, csr_ui);
    k_fill<<<hb, 256, 0, stream>>>(ei_iu, cur_iu, csr_iu);

    // ---- layer 0 (reads d_in, writes d_out halves) ----
    k_agg<<<NN, 128, 0, stream>>>(x_user, rp_ui, csr_ui, mean_item);
    k_agg<<<NN, 128, 0, stream>>>(x_item, rp_iu, csr_iu, mean_user);
    k_gemm_ln<<<256, 512, 0, stream>>>(mean_item, x_item, Wl_ui[0], bl_ui[0], Wr_ui[0],
                                       g_item[0], b_item[0], out_item);
    k_gemm_ln<<<256, 512, 0, stream>>>(mean_user, x_user, Wl_iu[0], bl_iu[0], Wr_iu[0],
                                       g_user[0], b_user[0], out_user);

    // ---- layer 1 (reads d_out, writes d_out in place; means computed first) ----
    k_agg<<<NN, 128, 0, stream>>>(out_user, rp_ui, csr_ui, mean_item);
    k_agg<<<NN, 128, 0, stream>>>(out_item, rp_iu, csr_iu, mean_user);
    k_gemm_ln<<<256, 512, 0, stream>>>(mean_item, out_item, Wl_ui[1], bl_ui[1], Wr_ui[1],
                                       g_item[1], b_item[1], out_item);
    k_gemm_ln<<<256, 512, 0, stream>>>(mean_user, out_user, Wl_iu[1], bl_iu[1], Wr_iu[1],
                                       g_user[1], b_user[1], out_user);
}

// Round 2
// 896.302 us; speedup vs baseline: 1.6204x; 1.6204x over previous
//
#include <hip/hip_runtime.h>

#define NN 100000
#define NE 600000
#define CC 128
#define NCHUNKS 49           // ceil(NN / 2048)
#define TILE_N 128           // nodes per block-iter in GEMM
#define KB 64                // k-chunk
#define NPG 8                // nodes per 32-lane group

// ---------------- CSR build ----------------

__global__ void k_zero(int* __restrict__ p, int n) {
    int i = blockIdx.x * blockDim.x + threadIdx.x;
    if (i < n) p[i] = 0;
}

__global__ void k_hist(const int* __restrict__ ei, int* __restrict__ cnt) {
    int e = blockIdx.x * blockDim.x + threadIdx.x;
    if (e < NE) atomicAdd(&cnt[ei[NE + e]], 1);
}

// chunk = 2048 elems, 256 thr x 8
__global__ void k_scan1(const int* __restrict__ deg, int* __restrict__ csum) {
    __shared__ int s[256];
    int c = blockIdx.x, t = threadIdx.x;
    int base = c * 2048 + t * 8;
    int v = 0;
#pragma unroll
    for (int u = 0; u < 8; ++u) { int i = base + u; if (i < NN) v += deg[i]; }
    s[t] = v; __syncthreads();
    for (int off = 128; off > 0; off >>= 1) {
        if (t < off) s[t] += s[t + off];
        __syncthreads();
    }
    if (t == 0) csum[c] = s[0];
}

__global__ void k_scan2(int* __restrict__ csum_ui, int* __restrict__ csum_iu,
                        int* __restrict__ rp_ui, int* __restrict__ rp_iu) {
    int* cs = blockIdx.x ? csum_iu : csum_ui;
    int* rp = blockIdx.x ? rp_iu : rp_ui;
    int run = 0;
    for (int i = 0; i < NCHUNKS; ++i) { int v = cs[i]; cs[i] = run; run += v; }
    rp[NN] = run;
}

__global__ void k_scan3(const int* __restrict__ csum, int* __restrict__ degcur,
                        int* __restrict__ rp) {
    __shared__ int s[256];
    int c = blockIdx.x, t = threadIdx.x;
    int base = c * 2048 + t * 8;
    int loc[8]; int v = 0;
#pragma unroll
    for (int u = 0; u < 8; ++u) { int i = base + u; loc[u] = (i < NN) ? degcur[i] : 0; v += loc[u]; }
    s[t] = v; __syncthreads();
    for (int off = 1; off < 256; off <<= 1) {
        int x = (t >= off) ? s[t - off] : 0;
        __syncthreads();
        s[t] += x;
        __syncthreads();
    }
    int pre = s[t] - v + csum[c];
#pragma unroll
    for (int u = 0; u < 8; ++u) {
        int i = base + u;
        if (i < NN) { rp[i] = pre; degcur[i] = pre; pre += loc[u]; }
    }
}

__global__ void k_fill(const int* __restrict__ ei, int* __restrict__ cur,
                       int* __restrict__ csr) {
    int e = blockIdx.x * blockDim.x + threadIdx.x;
    if (e < NE) {
        int src = ei[e], dst = ei[NE + e];
        int pos = atomicAdd(&cur[dst], 1);
        csr[pos] = src;
    }
}

// ---------------- aggregation: mean of neighbor rows ----------------
// 8 nodes/block, 32 lanes/node, float4 gathers (512B coalesced per row).

__global__ __launch_bounds__(256)
void k_agg(const float* __restrict__ xsrc, const int* __restrict__ rp,
           const int* __restrict__ csr, float* __restrict__ mean) {
    int t = threadIdx.x;
    int d = blockIdx.x * 8 + (t >> 5);
    if (d >= NN) return;
    int j0 = (t & 31) * 4;
    int b = rp[d], e = rp[d + 1];
    float4 acc = make_float4(0.f, 0.f, 0.f, 0.f);
    for (int i = b; i < e; ++i) {
        int s = csr[i];
        float4 v = *reinterpret_cast<const float4*>(xsrc + (size_t)s * CC + j0);
        acc.x += v.x; acc.y += v.y; acc.z += v.z; acc.w += v.w;
    }
    int deg = e - b;
    float inv = 1.f / (float)(deg > 1 ? deg : 1);
    acc.x *= inv; acc.y *= inv; acc.z *= inv; acc.w *= inv;
    *reinterpret_cast<float4*>(mean + (size_t)d * CC + j0) = acc;
}

// ---------------- fused [mean|x] @ W^T + b -> LN -> ReLU ----------------
// 512 thr = 16 groups of 32 lanes; each group: 8 nodes x (4 outputs/lane).
// Register-blocked: per 4 k-steps, 4 W b128 reads + 8 broadcast row b128 reads
// feed 128 FMAs -> VALU-bound.

__global__ __launch_bounds__(512, 4)
void k_gemm_ln(const float* __restrict__ mean, const float* __restrict__ xdst,
               const float* __restrict__ Wl, const float* __restrict__ bl,
               const float* __restrict__ Wr, const float* __restrict__ g,
               const float* __restrict__ bb, float* __restrict__ out) {
    __shared__ float WTc[KB][128];        // 32 KB  W^T chunk
    __shared__ float RC[TILE_N][KB];      // 32 KB  row chunk
    __shared__ float sbl[128], sg[128], sb[128];

    int t = threadIdx.x;
    if (t < 128) { sbl[t] = bl[t]; sg[t] = g[t]; sb[t] = bb[t]; }

    int gidx = t >> 5, jl = t & 31, j0 = jl * 4;
    int jW = t & 127, kq = t >> 7;        // W staging: col jW, k-range kq*16..+16
    int nR = t >> 2, pR = t & 3;          // row staging: node nR, 64B part pR

    for (int base = blockIdx.x * TILE_N; base < NN; base += gridDim.x * TILE_N) {
        float4 acc[NPG];
#pragma unroll
        for (int i = 0; i < NPG; ++i) acc[i] = make_float4(0.f, 0.f, 0.f, 0.f);

        for (int kc = 0; kc < 4; ++kc) {
            int k0 = kc * KB;
            __syncthreads();   // previous chunk's compute done before restage
            // ---- stage W^T chunk ----
            {
                const float* Wsrc = (k0 < 128) ? Wl : Wr;
                int kk0 = kq * 16;
                const float* wrow = Wsrc + (size_t)jW * CC + ((k0 & 127) + kk0);
#pragma unroll
                for (int u = 0; u < 4; ++u) {
                    float4 wv = *reinterpret_cast<const float4*>(wrow + u * 4);
                    WTc[kk0 + u * 4 + 0][jW] = wv.x;
                    WTc[kk0 + u * 4 + 1][jW] = wv.y;
                    WTc[kk0 + u * 4 + 2][jW] = wv.z;
                    WTc[kk0 + u * 4 + 3][jW] = wv.w;
                }
            }
            // ---- stage row chunk ----
            {
                const float* src = (k0 < 128) ? mean : xdst;
                int node = base + nR;
                int col0 = (k0 & 127) + pR * 16;
                if (node < NN) {
                    const float* rp_ = src + (size_t)node * CC + col0;
#pragma unroll
                    for (int u = 0; u < 4; ++u)
                        *reinterpret_cast<float4*>(&RC[nR][pR * 16 + u * 4]) =
                            *reinterpret_cast<const float4*>(rp_ + u * 4);
                } else {
#pragma unroll
                    for (int u = 0; u < 4; ++u)
                        *reinterpret_cast<float4*>(&RC[nR][pR * 16 + u * 4]) =
                            make_float4(0.f, 0.f, 0.f, 0.f);
                }
            }
            __syncthreads();
            // ---- compute ----
#pragma unroll
            for (int kk = 0; kk < KB; kk += 4) {
                float4 w[4];
#pragma unroll
                for (int u = 0; u < 4; ++u)
                    w[u] = *reinterpret_cast<const float4*>(&WTc[kk + u][j0]);
#pragma unroll
                for (int i = 0; i < NPG; ++i) {
                    float4 rv = *reinterpret_cast<const float4*>(&RC[gidx * NPG + i][kk]);
                    acc[i].x = fmaf(rv.x, w[0].x, acc[i].x);
                    acc[i].y = fmaf(rv.x, w[0].y, acc[i].y);
                    acc[i].z = fmaf(rv.x, w[0].z, acc[i].z);
                    acc[i].w = fmaf(rv.x, w[0].w, acc[i].w);
                    acc[i].x = fmaf(rv.y, w[1].x, acc[i].x);
                    acc[i].y = fmaf(rv.y, w[1].y, acc[i].y);
                    acc[i].z = fmaf(rv.y, w[1].z, acc[i].z);
                    acc[i].w = fmaf(rv.y, w[1].w, acc[i].w);
                    acc[i].x = fmaf(rv.z, w[2].x, acc[i].x);
                    acc[i].y = fmaf(rv.z, w[2].y, acc[i].y);
                    acc[i].z = fmaf(rv.z, w[2].z, acc[i].z);
                    acc[i].w = fmaf(rv.z, w[2].w, acc[i].w);
                    acc[i].x = fmaf(rv.w, w[3].x, acc[i].x);
                    acc[i].y = fmaf(rv.w, w[3].y, acc[i].y);
                    acc[i].z = fmaf(rv.w, w[3].z, acc[i].z);
                    acc[i].w = fmaf(rv.w, w[3].w, acc[i].w);
                }
            }
        }

        // ---- epilogue: +bias, LN, ReLU, store ----
#pragma unroll
        for (int i = 0; i < NPG; ++i) {
            float4 a = acc[i];
            a.x += sbl[j0 + 0]; a.y += sbl[j0 + 1];
            a.z += sbl[j0 + 2]; a.w += sbl[j0 + 3];
            float s1 = a.x + a.y + a.z + a.w;
            float s2 = a.x * a.x + a.y * a.y + a.z * a.z + a.w * a.w;
#pragma unroll
            for (int m = 1; m < 32; m <<= 1) {
                s1 += __shfl_xor(s1, m);
                s2 += __shfl_xor(s2, m);
            }
            float mu = s1 * (1.f / 128.f);
            float var = s2 * (1.f / 128.f) - mu * mu;
            float rstd = rsqrtf(var + 1e-5f);
            float4 o;
            o.x = fmaxf(0.f, (a.x - mu) * rstd * sg[j0 + 0] + sb[j0 + 0]);
            o.y = fmaxf(0.f, (a.y - mu) * rstd * sg[j0 + 1] + sb[j0 + 1]);
            o.z = fmaxf(0.f, (a.z - mu) * rstd * sg[j0 + 2] + sb[j0 + 2]);
            o.w = fmaxf(0.f, (a.w - mu) * rstd * sg[j0 + 3] + sb[j0 + 3]);
            int node = base + gidx * NPG + i;
            if (node < NN)
                *reinterpret_cast<float4*>(out + (size_t)node * CC + j0) = o;
        }
    }
}

// ---------------- launch ----------------

extern "C" void kernel_launch(void* const* d_in, const int* in_sizes, int n_in,
                              void* d_out, int out_size, void* d_ws, size_t ws_size,
                              hipStream_t stream) {
    const float* x_user = (const float*)d_in[0];
    const float* x_item = (const float*)d_in[1];
    const int* ei_ui = (const int*)d_in[2];
    const int* ei_iu = (const int*)d_in[3];

    const float* Wl_ui[2] = {(const float*)d_in[4],  (const float*)d_in[14]};
    const float* bl_ui[2] = {(const float*)d_in[5],  (const float*)d_in[15]};
    const float* Wr_ui[2] = {(const float*)d_in[6],  (const float*)d_in[16]};
    const float* Wl_iu[2] = {(const float*)d_in[7],  (const float*)d_in[17]};
    const float* bl_iu[2] = {(const float*)d_in[8],  (const float*)d_in[18]};
    const float* Wr_iu[2] = {(const float*)d_in[9],  (const float*)d_in[19]};
    const float* g_user[2] = {(const float*)d_in[10], (const float*)d_in[20]};
    const float* b_user[2] = {(const float*)d_in[11], (const float*)d_in[21]};
    const float* g_item[2] = {(const float*)d_in[12], (const float*)d_in[22]};
    const float* b_item[2] = {(const float*)d_in[13], (const float*)d_in[23]};

    auto align = [](size_t x) { return (x + 255) & ~(size_t)255; };
    char* w = (char*)d_ws;
    int* cur_ui = (int*)w;
    int* cur_iu = cur_ui + NN;
    w += align((size_t)2 * NN * 4);
    int* csum_ui = (int*)w; w += align(64 * 4);
    int* csum_iu = (int*)w; w += align(64 * 4);
    int* rp_ui = (int*)w; w += align((size_t)(NN + 1) * 4);
    int* rp_iu = (int*)w; w += align((size_t)(NN + 1) * 4);
    int* csr_ui = (int*)w; w += align((size_t)NE * 4);
    int* csr_iu = (int*)w; w += align((size_t)NE * 4);
    float* mean_item = (float*)w; w += align((size_t)NN * CC * 4);
    float* mean_user = (float*)w; w += align((size_t)NN * CC * 4);

    float* out_user = (float*)d_out;
    float* out_item = (float*)d_out + (size_t)NN * CC;

    int hb = (NE + 255) / 256;
    int ab = (NN + 7) / 8;

    // ---- CSR build (shared by both layers) ----
    k_zero<<<(2 * NN + 255) / 256, 256, 0, stream>>>(cur_ui, 2 * NN);
    k_hist<<<hb, 256, 0, stream>>>(ei_ui, cur_ui);
    k_hist<<<hb, 256, 0, stream>>>(ei_iu, cur_iu);
    k_scan1<<<NCHUNKS, 256, 0, stream>>>(cur_ui, csum_ui);
    k_scan1<<<NCHUNKS, 256, 0, stream>>>(cur_iu, csum_iu);
    k_scan2<<<2, 1, 0, stream>>>(csum_ui, csum_iu, rp_ui, rp_iu);
    k_scan3<<<NCHUNKS, 256, 0, stream>>>(csum_ui, cur_ui, rp_ui);
    k_scan3<<<NCHUNKS, 256, 0, stream>>>(csum_iu, cur_iu, rp_iu);
    k_fill<<<hb, 256, 0, stream>>>(ei_ui, cur_ui, csr_ui);
    k_fill<<<hb, 256, 0, stream>>>(ei_iu, cur_iu, csr_iu);

    // ---- layer 0 ----
    k_agg<<<ab, 256, 0, stream>>>(x_user, rp_ui, csr_ui, mean_item);
    k_agg<<<ab, 256, 0, stream>>>(x_item, rp_iu, csr_iu, mean_user);
    k_gemm_ln<<<512, 512, 0, stream>>>(mean_item, x_item, Wl_ui[0], bl_ui[0], Wr_ui[0],
                                       g_item[0], b_item[0], out_item);
    k_gemm_ln<<<512, 512, 0, stream>>>(mean_user, x_user, Wl_iu[0], bl_iu[0], Wr_iu[0],
                                       g_user[0], b_user[0], out_user);

    // ---- layer 1 (in place on d_out halves; means first) ----
    k_agg<<<ab, 256, 0, stream>>>(out_user, rp_ui, csr_ui, mean_item);
    k_agg<<<ab, 256, 0, stream>>>(out_item, rp_iu, csr_iu, mean_user);
    k_gemm_ln<<<512, 512, 0, stream>>>(mean_item, out_item, Wl_ui[1], bl_ui[1], Wr_ui[1],
                                       g_item[1], b_item[1], out_item);
    k_gemm_ln<<<512, 512, 0, stream>>>(mean_user, out_user, Wl_iu[1], bl_iu[1], Wr_iu[1],
                                       g_user[1], b_user[1], out_user);
}

// Round 3
// 599.572 us; speedup vs baseline: 2.4224x; 1.4949x over previous
//
#include <hip/hip_runtime.h>

#define NN 100000
#define NE 600000
#define CC 128
#define NCHUNKS 49           // ceil(NN / 2048)
#define TILE_N 128           // nodes per block in GEMM
#define GB ((NN + TILE_N - 1) / TILE_N)

typedef __attribute__((ext_vector_type(8))) short short8v;
typedef __attribute__((ext_vector_type(4))) float float4v;
typedef __attribute__((ext_vector_type(4))) unsigned short ushort4v;

__device__ __forceinline__ unsigned short f2bf(float f) {
    union { float f; unsigned u; } c; c.f = f;
    unsigned r = c.u + 0x7FFFu + ((c.u >> 16) & 1u);   // RNE
    return (unsigned short)(r >> 16);
}

// ---------------- CSR build ----------------

__global__ void k_zero(int* __restrict__ p, int n) {
    int i = blockIdx.x * blockDim.x + threadIdx.x;
    if (i < n) p[i] = 0;
}

__global__ void k_hist(const int* __restrict__ ei, int* __restrict__ cnt) {
    int e = blockIdx.x * blockDim.x + threadIdx.x;
    if (e < NE) atomicAdd(&cnt[ei[NE + e]], 1);
}

__global__ void k_scan1(const int* __restrict__ deg, int* __restrict__ csum) {
    __shared__ int s[256];
    int c = blockIdx.x, t = threadIdx.x;
    int base = c * 2048 + t * 8;
    int v = 0;
#pragma unroll
    for (int u = 0; u < 8; ++u) { int i = base + u; if (i < NN) v += deg[i]; }
    s[t] = v; __syncthreads();
    for (int off = 128; off > 0; off >>= 1) {
        if (t < off) s[t] += s[t + off];
        __syncthreads();
    }
    if (t == 0) csum[c] = s[0];
}

__global__ void k_scan2(int* __restrict__ csum_ui, int* __restrict__ csum_iu,
                        int* __restrict__ rp_ui, int* __restrict__ rp_iu) {
    int* cs = blockIdx.x ? csum_iu : csum_ui;
    int* rp = blockIdx.x ? rp_iu : rp_ui;
    int run = 0;
    for (int i = 0; i < NCHUNKS; ++i) { int v = cs[i]; cs[i] = run; run += v; }
    rp[NN] = run;
}

__global__ void k_scan3(const int* __restrict__ csum, int* __restrict__ degcur,
                        int* __restrict__ rp) {
    __shared__ int s[256];
    int c = blockIdx.x, t = threadIdx.x;
    int base = c * 2048 + t * 8;
    int loc[8]; int v = 0;
#pragma unroll
    for (int u = 0; u < 8; ++u) { int i = base + u; loc[u] = (i < NN) ? degcur[i] : 0; v += loc[u]; }
    s[t] = v; __syncthreads();
    for (int off = 1; off < 256; off <<= 1) {
        int x = (t >= off) ? s[t - off] : 0;
        __syncthreads();
        s[t] += x;
        __syncthreads();
    }
    int pre = s[t] - v + csum[c];
#pragma unroll
    for (int u = 0; u < 8; ++u) {
        int i = base + u;
        if (i < NN) { rp[i] = pre; degcur[i] = pre; pre += loc[u]; }
    }
}

__global__ void k_fill(const int* __restrict__ ei, int* __restrict__ cur,
                       int* __restrict__ csr) {
    int e = blockIdx.x * blockDim.x + threadIdx.x;
    if (e < NE) {
        int src = ei[e], dst = ei[NE + e];
        int pos = atomicAdd(&cur[dst], 1);
        csr[pos] = src;
    }
}

// ---------------- aggregation: mean of neighbor rows ----------------

__global__ __launch_bounds__(256)
void k_agg(const float* __restrict__ xsrc, const int* __restrict__ rp,
           const int* __restrict__ csr, float* __restrict__ mean) {
    int t = threadIdx.x;
    int d = blockIdx.x * 8 + (t >> 5);
    if (d >= NN) return;
    int j0 = (t & 31) * 4;
    int b = rp[d], e = rp[d + 1];
    float4 acc = make_float4(0.f, 0.f, 0.f, 0.f);
    for (int i = b; i < e; ++i) {
        int s = csr[i];
        float4 v = *reinterpret_cast<const float4*>(xsrc + (size_t)s * CC + j0);
        acc.x += v.x; acc.y += v.y; acc.z += v.z; acc.w += v.w;
    }
    int deg = e - b;
    float inv = 1.f / (float)(deg > 1 ? deg : 1);
    acc.x *= inv; acc.y *= inv; acc.z *= inv; acc.w *= inv;
    *reinterpret_cast<float4*>(mean + (size_t)d * CC + j0) = acc;
}

// ---------------- MFMA fused [mean|x] @ W^T + b -> LN -> ReLU ----------------
// 512 thr = 8 waves (2 m-groups x 4 n-groups). Tile: 128 nodes x 128 cols, K=256.
// A: LDS [128][256] bf16, XOR-swizzled (byte ^= (row&7)<<4). B: global->reg frags
// (W stored [out][k] = B^T layout). Epilogue: biased acc -> LDS fp32 (reuse A buf,
// same swizzle) -> transposed LN -> coalesced float4 stores.

__global__ __launch_bounds__(512, 4)
void k_gemm_ln(const float* __restrict__ mean, const float* __restrict__ xdst,
               const float* __restrict__ Wl, const float* __restrict__ bl,
               const float* __restrict__ Wr, const float* __restrict__ g,
               const float* __restrict__ bb, float* __restrict__ out) {
    __shared__ char sA[TILE_N * 512];              // 64 KB: bf16 A tile, then fp32 LN buf
    __shared__ float sbl[128], sg[128], sb[128];

    int t = threadIdx.x;
    int base = blockIdx.x * TILE_N;

    if (t < 128) { sbl[t] = bl[t]; sg[t] = g[t]; sb[t] = bb[t]; }

    // ---- stage A tile: row r = t>>2, quarter q = t&3 (interleaved 16B chunks) ----
    {
        int r = t >> 2, q = t & 3;
        int node = base + r;
        bool valid = node < NN;
        const float* msrc = mean + (size_t)node * CC;
        const float* xsrc = xdst + (size_t)node * CC;
#pragma unroll
        for (int u = 0; u < 8; ++u) {
            int c = q * 4 + u * 16;                         // float col in [0,128)
            float4 f = valid ? *reinterpret_cast<const float4*>(msrc + c)
                             : make_float4(0.f, 0.f, 0.f, 0.f);
            ushort4v h; h.x = f2bf(f.x); h.y = f2bf(f.y); h.z = f2bf(f.z); h.w = f2bf(f.w);
            int byte = (r * 512 + c * 2) ^ ((r & 7) << 4);
            *reinterpret_cast<ushort4v*>(sA + byte) = h;
            float4 f2 = valid ? *reinterpret_cast<const float4*>(xsrc + c)
                              : make_float4(0.f, 0.f, 0.f, 0.f);
            ushort4v h2; h2.x = f2bf(f2.x); h2.y = f2bf(f2.y); h2.z = f2bf(f2.z); h2.w = f2bf(f2.w);
            int byte2 = (r * 512 + 256 + c * 2) ^ ((r & 7) << 4);
            *reinterpret_cast<ushort4v*>(sA + byte2) = h2;
        }
    }
    __syncthreads();

    int wid = t >> 6, l = t & 63;
    int mg = wid >> 2, ng = wid & 3;
    int l15 = l & 15, l4 = l >> 4;

    float4v acc[4][2];
#pragma unroll
    for (int mt = 0; mt < 4; ++mt)
#pragma unroll
        for (int nt = 0; nt < 2; ++nt)
            acc[mt][nt] = (float4v){0.f, 0.f, 0.f, 0.f};

#pragma unroll
    for (int khalf = 0; khalf < 2; ++khalf) {
        // ---- B frags: global -> reg (W row j = output col, contiguous k) ----
        const float* Wsrc = khalf ? Wr : Wl;
        short8v bfrag[2][4];
#pragma unroll
        for (int nt = 0; nt < 2; ++nt) {
            int j = ng * 32 + nt * 16 + l15;
            const float* wr_ = Wsrc + (size_t)j * CC + l4 * 8;
#pragma unroll
            for (int kk4 = 0; kk4 < 4; ++kk4) {
                float4 a = *reinterpret_cast<const float4*>(wr_ + kk4 * 32);
                float4 b2 = *reinterpret_cast<const float4*>(wr_ + kk4 * 32 + 4);
                short8v h;
                h[0] = (short)f2bf(a.x);  h[1] = (short)f2bf(a.y);
                h[2] = (short)f2bf(a.z);  h[3] = (short)f2bf(a.w);
                h[4] = (short)f2bf(b2.x); h[5] = (short)f2bf(b2.y);
                h[6] = (short)f2bf(b2.z); h[7] = (short)f2bf(b2.w);
                bfrag[nt][kk4] = h;
            }
        }
        // ---- MFMA over this K-half ----
#pragma unroll
        for (int kk4 = 0; kk4 < 4; ++kk4) {
            short8v af[4];
#pragma unroll
            for (int mt = 0; mt < 4; ++mt) {
                int row = mg * 64 + mt * 16 + l15;
                int byte = (row * 512 + l4 * 16 + (khalf * 4 + kk4) * 64) ^ ((row & 7) << 4);
                af[mt] = *reinterpret_cast<short8v*>(sA + byte);
            }
#pragma unroll
            for (int mt = 0; mt < 4; ++mt)
#pragma unroll
                for (int nt = 0; nt < 2; ++nt)
                    acc[mt][nt] = __builtin_amdgcn_mfma_f32_16x16x32_bf16(
                        af[mt], bfrag[nt][kk4], acc[mt][nt], 0, 0, 0);
        }
    }
    __syncthreads();   // A tile free; reuse as fp32 LN buffer

    // ---- scatter biased acc to LDS fp32 (same XOR swizzle) ----
    float* fb = reinterpret_cast<float*>(sA);
#pragma unroll
    for (int mt = 0; mt < 4; ++mt)
#pragma unroll
        for (int r4 = 0; r4 < 4; ++r4) {
            int node = mg * 64 + mt * 16 + l4 * 4 + r4;
#pragma unroll
            for (int nt = 0; nt < 2; ++nt) {
                int col = ng * 32 + nt * 16 + l15;
                float v = acc[mt][nt][r4] + sbl[col];
                int byte = (node * 512 + col * 4) ^ ((node & 7) << 4);
                *reinterpret_cast<float*>(sA + byte) = v;
            }
        }
    __syncthreads();

    // ---- transposed LN: thread t -> node t>>2, quarter t&3 ----
    {
        int nn_ = t >> 2, qq = t & 3;
        int gnode = base + nn_;
        float s1 = 0.f, s2 = 0.f;
        float4 vv[8];
#pragma unroll
        for (int u = 0; u < 8; ++u) {
            int c = qq * 4 + u * 16;
            int byte = (nn_ * 512 + c * 4) ^ ((nn_ & 7) << 4);
            float4 vx = *reinterpret_cast<float4*>(sA + byte);
            vv[u] = vx;
            s1 += vx.x + vx.y + vx.z + vx.w;
            s2 += vx.x * vx.x + vx.y * vx.y + vx.z * vx.z + vx.w * vx.w;
        }
        s1 += __shfl_xor(s1, 1); s1 += __shfl_xor(s1, 2);
        s2 += __shfl_xor(s2, 1); s2 += __shfl_xor(s2, 2);
        float mu = s1 * (1.f / 128.f);
        float var = s2 * (1.f / 128.f) - mu * mu;
        float rstd = rsqrtf(var + 1e-5f);
        if (gnode < NN) {
            float* op = out + (size_t)gnode * CC;
#pragma unroll
            for (int u = 0; u < 8; ++u) {
                int c = qq * 4 + u * 16;
                float4 vx = vv[u];
                float4 o;
                o.x = fmaxf(0.f, (vx.x - mu) * rstd * sg[c + 0] + sb[c + 0]);
                o.y = fmaxf(0.f, (vx.y - mu) * rstd * sg[c + 1] + sb[c + 1]);
                o.z = fmaxf(0.f, (vx.z - mu) * rstd * sg[c + 2] + sb[c + 2]);
                o.w = fmaxf(0.f, (vx.w - mu) * rstd * sg[c + 3] + sb[c + 3]);
                *reinterpret_cast<float4*>(op + c) = o;
            }
        }
    }
}

// ---------------- launch ----------------

extern "C" void kernel_launch(void* const* d_in, const int* in_sizes, int n_in,
                              void* d_out, int out_size, void* d_ws, size_t ws_size,
                              hipStream_t stream) {
    const float* x_user = (const float*)d_in[0];
    const float* x_item = (const float*)d_in[1];
    const int* ei_ui = (const int*)d_in[2];
    const int* ei_iu = (const int*)d_in[3];

    const float* Wl_ui[2] = {(const float*)d_in[4],  (const float*)d_in[14]};
    const float* bl_ui[2] = {(const float*)d_in[5],  (const float*)d_in[15]};
    const float* Wr_ui[2] = {(const float*)d_in[6],  (const float*)d_in[16]};
    const float* Wl_iu[2] = {(const float*)d_in[7],  (const float*)d_in[17]};
    const float* bl_iu[2] = {(const float*)d_in[8],  (const float*)d_in[18]};
    const float* Wr_iu[2] = {(const float*)d_in[9],  (const float*)d_in[19]};
    const float* g_user[2] = {(const float*)d_in[10], (const float*)d_in[20]};
    const float* b_user[2] = {(const float*)d_in[11], (const float*)d_in[21]};
    const float* g_item[2] = {(const float*)d_in[12], (const float*)d_in[22]};
    const float* b_item[2] = {(const float*)d_in[13], (const float*)d_in[23]};

    auto align = [](size_t x) { return (x + 255) & ~(size_t)255; };
    char* w = (char*)d_ws;
    int* cur_ui = (int*)w;
    int* cur_iu = cur_ui + NN;
    w += align((size_t)2 * NN * 4);
    int* csum_ui = (int*)w; w += align(64 * 4);
    int* csum_iu = (int*)w; w += align(64 * 4);
    int* rp_ui = (int*)w; w += align((size_t)(NN + 1) * 4);
    int* rp_iu = (int*)w; w += align((size_t)(NN + 1) * 4);
    int* csr_ui = (int*)w; w += align((size_t)NE * 4);
    int* csr_iu = (int*)w; w += align((size_t)NE * 4);
    float* mean_item = (float*)w; w += align((size_t)NN * CC * 4);
    float* mean_user = (float*)w; w += align((size_t)NN * CC * 4);

    float* out_user = (float*)d_out;
    float* out_item = (float*)d_out + (size_t)NN * CC;

    int hb = (NE + 255) / 256;
    int ab = (NN + 7) / 8;

    // ---- CSR build (shared by both layers) ----
    k_zero<<<(2 * NN + 255) / 256, 256, 0, stream>>>(cur_ui, 2 * NN);
    k_hist<<<hb, 256, 0, stream>>>(ei_ui, cur_ui);
    k_hist<<<hb, 256, 0, stream>>>(ei_iu, cur_iu);
    k_scan1<<<NCHUNKS, 256, 0, stream>>>(cur_ui, csum_ui);
    k_scan1<<<NCHUNKS, 256, 0, stream>>>(cur_iu, csum_iu);
    k_scan2<<<2, 1, 0, stream>>>(csum_ui, csum_iu, rp_ui, rp_iu);
    k_scan3<<<NCHUNKS, 256, 0, stream>>>(csum_ui, cur_ui, rp_ui);
    k_scan3<<<NCHUNKS, 256, 0, stream>>>(csum_iu, cur_iu, rp_iu);
    k_fill<<<hb, 256, 0, stream>>>(ei_ui, cur_ui, csr_ui);
    k_fill<<<hb, 256, 0, stream>>>(ei_iu, cur_iu, csr_iu);

    // ---- layer 0 ----
    k_agg<<<ab, 256, 0, stream>>>(x_user, rp_ui, csr_ui, mean_item);
    k_agg<<<ab, 256, 0, stream>>>(x_item, rp_iu, csr_iu, mean_user);
    k_gemm_ln<<<GB, 512, 0, stream>>>(mean_item, x_item, Wl_ui[0], bl_ui[0], Wr_ui[0],
                                      g_item[0], b_item[0], out_item);
    k_gemm_ln<<<GB, 512, 0, stream>>>(mean_user, x_user, Wl_iu[0], bl_iu[0], Wr_iu[0],
                                      g_user[0], b_user[0], out_user);

    // ---- layer 1 (in place on d_out halves; means first) ----
    k_agg<<<ab, 256, 0, stream>>>(out_user, rp_ui, csr_ui, mean_item);
    k_agg<<<ab, 256, 0, stream>>>(out_item, rp_iu, csr_iu, mean_user);
    k_gemm_ln<<<GB, 512, 0, stream>>>(mean_item, out_item, Wl_ui[1], bl_ui[1], Wr_ui[1],
                                      g_item[1], b_item[1], out_item);
    k_gemm_ln<<<GB, 512, 0, stream>>>(mean_user, out_user, Wl_iu[1], bl_iu[1], Wr_iu[1],
                                      g_user[1], b_user[1], out_user);
}

// Round 4
// 530.496 us; speedup vs baseline: 2.7378x; 1.1302x over previous
//
#include <hip/hip_runtime.h>

#define NN 100000
#define NE 600000
#define CC 128
#define NCHUNKS 49           // ceil(NN / 2048)
#define TILE_N 128           // nodes per block in GEMM
#define GB ((NN + TILE_N - 1) / TILE_N)

typedef __attribute__((ext_vector_type(8))) short short8v;
typedef __attribute__((ext_vector_type(4))) float float4v;
typedef __attribute__((ext_vector_type(4))) unsigned short ushort4v;

__device__ __forceinline__ unsigned short f2bf(float f) {
    union { float f; unsigned u; } c; c.f = f;
    unsigned r = c.u + 0x7FFFu + ((c.u >> 16) & 1u);   // RNE
    return (unsigned short)(r >> 16);
}

// ---------------- CSR build ----------------

__global__ void k_zero(int* __restrict__ p, int n) {
    int i = blockIdx.x * blockDim.x + threadIdx.x;
    if (i < n) p[i] = 0;
}

__global__ void k_hist(const int* __restrict__ ei, int* __restrict__ cnt) {
    int e = blockIdx.x * blockDim.x + threadIdx.x;
    if (e < NE) atomicAdd(&cnt[ei[NE + e]], 1);
}

__global__ void k_scan1(const int* __restrict__ deg, int* __restrict__ csum) {
    __shared__ int s[256];
    int c = blockIdx.x, t = threadIdx.x;
    int base = c * 2048 + t * 8;
    int v = 0;
#pragma unroll
    for (int u = 0; u < 8; ++u) { int i = base + u; if (i < NN) v += deg[i]; }
    s[t] = v; __syncthreads();
    for (int off = 128; off > 0; off >>= 1) {
        if (t < off) s[t] += s[t + off];
        __syncthreads();
    }
    if (t == 0) csum[c] = s[0];
}

__global__ void k_scan2(int* __restrict__ csum_ui, int* __restrict__ csum_iu,
                        int* __restrict__ rp_ui, int* __restrict__ rp_iu) {
    int* cs = blockIdx.x ? csum_iu : csum_ui;
    int* rp = blockIdx.x ? rp_iu : rp_ui;
    int run = 0;
    for (int i = 0; i < NCHUNKS; ++i) { int v = cs[i]; cs[i] = run; run += v; }
    rp[NN] = run;
}

__global__ void k_scan3(const int* __restrict__ csum, int* __restrict__ degcur,
                        int* __restrict__ rp) {
    __shared__ int s[256];
    int c = blockIdx.x, t = threadIdx.x;
    int base = c * 2048 + t * 8;
    int loc[8]; int v = 0;
#pragma unroll
    for (int u = 0; u < 8; ++u) { int i = base + u; loc[u] = (i < NN) ? degcur[i] : 0; v += loc[u]; }
    s[t] = v; __syncthreads();
    for (int off = 1; off < 256; off <<= 1) {
        int x = (t >= off) ? s[t - off] : 0;
        __syncthreads();
        s[t] += x;
        __syncthreads();
    }
    int pre = s[t] - v + csum[c];
#pragma unroll
    for (int u = 0; u < 8; ++u) {
        int i = base + u;
        if (i < NN) { rp[i] = pre; degcur[i] = pre; pre += loc[u]; }
    }
}

__global__ void k_fill(const int* __restrict__ ei, int* __restrict__ cur,
                       int* __restrict__ csr) {
    int e = blockIdx.x * blockDim.x + threadIdx.x;
    if (e < NE) {
        int src = ei[e], dst = ei[NE + e];
        int pos = atomicAdd(&cur[dst], 1);
        csr[pos] = src;
    }
}

// ---------------- aggregation: mean of neighbor rows -> bf16 ----------------
// 8 nodes/block, 32 lanes/node. 4-way unrolled gather: 4 independent row loads
// in flight per group (MLP), 2-way tail. Mean written bf16 (same rounding as
// the old fp32->staging-convert path).

__global__ __launch_bounds__(256)
void k_agg(const float* __restrict__ xsrc, const int* __restrict__ rp,
           const int* __restrict__ csr, unsigned short* __restrict__ meanb) {
    int t = threadIdx.x;
    int d = blockIdx.x * 8 + (t >> 5);
    if (d >= NN) return;
    int j0 = (t & 31) * 4;
    int b = rp[d], e = rp[d + 1];
    float4 a0 = make_float4(0.f, 0.f, 0.f, 0.f);
    float4 a1 = a0, a2 = a0, a3 = a0;
    int i = b;
    for (; i + 4 <= e; i += 4) {
        int s0 = csr[i], s1 = csr[i + 1], s2 = csr[i + 2], s3 = csr[i + 3];
        float4 v0 = *reinterpret_cast<const float4*>(xsrc + (size_t)s0 * CC + j0);
        float4 v1 = *reinterpret_cast<const float4*>(xsrc + (size_t)s1 * CC + j0);
        float4 v2 = *reinterpret_cast<const float4*>(xsrc + (size_t)s2 * CC + j0);
        float4 v3 = *reinterpret_cast<const float4*>(xsrc + (size_t)s3 * CC + j0);
        a0.x += v0.x; a0.y += v0.y; a0.z += v0.z; a0.w += v0.w;
        a1.x += v1.x; a1.y += v1.y; a1.z += v1.z; a1.w += v1.w;
        a2.x += v2.x; a2.y += v2.y; a2.z += v2.z; a2.w += v2.w;
        a3.x += v3.x; a3.y += v3.y; a3.z += v3.z; a3.w += v3.w;
    }
    for (; i + 2 <= e; i += 2) {
        int s0 = csr[i], s1 = csr[i + 1];
        float4 v0 = *reinterpret_cast<const float4*>(xsrc + (size_t)s0 * CC + j0);
        float4 v1 = *reinterpret_cast<const float4*>(xsrc + (size_t)s1 * CC + j0);
        a0.x += v0.x; a0.y += v0.y; a0.z += v0.z; a0.w += v0.w;
        a1.x += v1.x; a1.y += v1.y; a1.z += v1.z; a1.w += v1.w;
    }
    if (i < e) {
        int s0 = csr[i];
        float4 v0 = *reinterpret_cast<const float4*>(xsrc + (size_t)s0 * CC + j0);
        a0.x += v0.x; a0.y += v0.y; a0.z += v0.z; a0.w += v0.w;
    }
    float4 acc;
    acc.x = (a0.x + a1.x) + (a2.x + a3.x);
    acc.y = (a0.y + a1.y) + (a2.y + a3.y);
    acc.z = (a0.z + a1.z) + (a2.z + a3.z);
    acc.w = (a0.w + a1.w) + (a2.w + a3.w);
    int deg = e - b;
    float inv = 1.f / (float)(deg > 1 ? deg : 1);
    ushort4v h;
    h.x = f2bf(acc.x * inv); h.y = f2bf(acc.y * inv);
    h.z = f2bf(acc.z * inv); h.w = f2bf(acc.w * inv);
    *reinterpret_cast<ushort4v*>(meanb + (size_t)d * CC + j0) = h;
}

// ---------------- MFMA fused [mean|x] @ W^T + b -> LN -> ReLU ----------------
// 512 thr = 8 waves (2 m-groups x 4 n-groups). Tile: 128 nodes x 128 cols, K=256.
// A: LDS [128][256] bf16, XOR-swizzled (byte ^= (row&7)<<4). mean half already
// bf16 (direct copy); x half converted in-flight. B: global->reg frags.
// Epilogue: biased acc -> LDS fp32 (same swizzle) -> transposed LN -> stores.

__global__ __launch_bounds__(512, 4)
void k_gemm_ln(const unsigned short* __restrict__ meanb, const float* __restrict__ xdst,
               const float* __restrict__ Wl, const float* __restrict__ bl,
               const float* __restrict__ Wr, const float* __restrict__ g,
               const float* __restrict__ bb, float* __restrict__ out) {
    __shared__ char sA[TILE_N * 512];              // 64 KB: bf16 A tile, then fp32 LN buf
    __shared__ float sbl[128], sg[128], sb[128];

    int t = threadIdx.x;
    int base = blockIdx.x * TILE_N;

    if (t < 128) { sbl[t] = bl[t]; sg[t] = g[t]; sb[t] = bb[t]; }

    // ---- stage A tile: row r = t>>2, quarter q = t&3 ----
    {
        int r = t >> 2, q = t & 3;
        int node = base + r;
        bool valid = node < NN;
        const unsigned short* msrc = meanb + (size_t)node * CC;
        const float* xsrc = xdst + (size_t)node * CC;
#pragma unroll
        for (int u = 0; u < 8; ++u) {
            int c = q * 4 + u * 16;                         // col in [0,128)
            ushort4v h = valid ? *reinterpret_cast<const ushort4v*>(msrc + c)
                               : (ushort4v){0, 0, 0, 0};
            int byte = (r * 512 + c * 2) ^ ((r & 7) << 4);
            *reinterpret_cast<ushort4v*>(sA + byte) = h;
            float4 f2 = valid ? *reinterpret_cast<const float4*>(xsrc + c)
                              : make_float4(0.f, 0.f, 0.f, 0.f);
            ushort4v h2; h2.x = f2bf(f2.x); h2.y = f2bf(f2.y); h2.z = f2bf(f2.z); h2.w = f2bf(f2.w);
            int byte2 = (r * 512 + 256 + c * 2) ^ ((r & 7) << 4);
            *reinterpret_cast<ushort4v*>(sA + byte2) = h2;
        }
    }
    __syncthreads();

    int wid = t >> 6, l = t & 63;
    int mg = wid >> 2, ng = wid & 3;
    int l15 = l & 15, l4 = l >> 4;

    float4v acc[4][2];
#pragma unroll
    for (int mt = 0; mt < 4; ++mt)
#pragma unroll
        for (int nt = 0; nt < 2; ++nt)
            acc[mt][nt] = (float4v){0.f, 0.f, 0.f, 0.f};

#pragma unroll
    for (int khalf = 0; khalf < 2; ++khalf) {
        const float* Wsrc = khalf ? Wr : Wl;
        short8v bfrag[2][4];
#pragma unroll
        for (int nt = 0; nt < 2; ++nt) {
            int j = ng * 32 + nt * 16 + l15;
            const float* wr_ = Wsrc + (size_t)j * CC + l4 * 8;
#pragma unroll
            for (int kk4 = 0; kk4 < 4; ++kk4) {
                float4 a = *reinterpret_cast<const float4*>(wr_ + kk4 * 32);
                float4 b2 = *reinterpret_cast<const float4*>(wr_ + kk4 * 32 + 4);
                short8v h;
                h[0] = (short)f2bf(a.x);  h[1] = (short)f2bf(a.y);
                h[2] = (short)f2bf(a.z);  h[3] = (short)f2bf(a.w);
                h[4] = (short)f2bf(b2.x); h[5] = (short)f2bf(b2.y);
                h[6] = (short)f2bf(b2.z); h[7] = (short)f2bf(b2.w);
                bfrag[nt][kk4] = h;
            }
        }
#pragma unroll
        for (int kk4 = 0; kk4 < 4; ++kk4) {
            short8v af[4];
#pragma unroll
            for (int mt = 0; mt < 4; ++mt) {
                int row = mg * 64 + mt * 16 + l15;
                int byte = (row * 512 + l4 * 16 + (khalf * 4 + kk4) * 64) ^ ((row & 7) << 4);
                af[mt] = *reinterpret_cast<short8v*>(sA + byte);
            }
#pragma unroll
            for (int mt = 0; mt < 4; ++mt)
#pragma unroll
                for (int nt = 0; nt < 2; ++nt)
                    acc[mt][nt] = __builtin_amdgcn_mfma_f32_16x16x32_bf16(
                        af[mt], bfrag[nt][kk4], acc[mt][nt], 0, 0, 0);
        }
    }
    __syncthreads();   // A tile free; reuse as fp32 LN buffer

    // ---- scatter biased acc to LDS fp32 (same XOR swizzle) ----
#pragma unroll
    for (int mt = 0; mt < 4; ++mt)
#pragma unroll
        for (int r4 = 0; r4 < 4; ++r4) {
            int node = mg * 64 + mt * 16 + l4 * 4 + r4;
#pragma unroll
            for (int nt = 0; nt < 2; ++nt) {
                int col = ng * 32 + nt * 16 + l15;
                float v = acc[mt][nt][r4] + sbl[col];
                int byte = (node * 512 + col * 4) ^ ((node & 7) << 4);
                *reinterpret_cast<float*>(sA + byte) = v;
            }
        }
    __syncthreads();

    // ---- transposed LN: thread t -> node t>>2, quarter t&3 ----
    {
        int nn_ = t >> 2, qq = t & 3;
        int gnode = base + nn_;
        float s1 = 0.f, s2 = 0.f;
        float4 vv[8];
#pragma unroll
        for (int u = 0; u < 8; ++u) {
            int c = qq * 4 + u * 16;
            int byte = (nn_ * 512 + c * 4) ^ ((nn_ & 7) << 4);
            float4 vx = *reinterpret_cast<float4*>(sA + byte);
            vv[u] = vx;
            s1 += vx.x + vx.y + vx.z + vx.w;
            s2 += vx.x * vx.x + vx.y * vx.y + vx.z * vx.z + vx.w * vx.w;
        }
        s1 += __shfl_xor(s1, 1); s1 += __shfl_xor(s1, 2);
        s2 += __shfl_xor(s2, 1); s2 += __shfl_xor(s2, 2);
        float mu = s1 * (1.f / 128.f);
        float var = s2 * (1.f / 128.f) - mu * mu;
        float rstd = rsqrtf(var + 1e-5f);
        if (gnode < NN) {
            float* op = out + (size_t)gnode * CC;
#pragma unroll
            for (int u = 0; u < 8; ++u) {
                int c = qq * 4 + u * 16;
                float4 vx = vv[u];
                float4 o;
                o.x = fmaxf(0.f, (vx.x - mu) * rstd * sg[c + 0] + sb[c + 0]);
                o.y = fmaxf(0.f, (vx.y - mu) * rstd * sg[c + 1] + sb[c + 1]);
                o.z = fmaxf(0.f, (vx.z - mu) * rstd * sg[c + 2] + sb[c + 2]);
                o.w = fmaxf(0.f, (vx.w - mu) * rstd * sg[c + 3] + sb[c + 3]);
                *reinterpret_cast<float4*>(op + c) = o;
            }
        }
    }
}

// ---------------- launch ----------------

extern "C" void kernel_launch(void* const* d_in, const int* in_sizes, int n_in,
                              void* d_out, int out_size, void* d_ws, size_t ws_size,
                              hipStream_t stream) {
    const float* x_user = (const float*)d_in[0];
    const float* x_item = (const float*)d_in[1];
    const int* ei_ui = (const int*)d_in[2];
    const int* ei_iu = (const int*)d_in[3];

    const float* Wl_ui[2] = {(const float*)d_in[4],  (const float*)d_in[14]};
    const float* bl_ui[2] = {(const float*)d_in[5],  (const float*)d_in[15]};
    const float* Wr_ui[2] = {(const float*)d_in[6],  (const float*)d_in[16]};
    const float* Wl_iu[2] = {(const float*)d_in[7],  (const float*)d_in[17]};
    const float* bl_iu[2] = {(const float*)d_in[8],  (const float*)d_in[18]};
    const float* Wr_iu[2] = {(const float*)d_in[9],  (const float*)d_in[19]};
    const float* g_user[2] = {(const float*)d_in[10], (const float*)d_in[20]};
    const float* b_user[2] = {(const float*)d_in[11], (const float*)d_in[21]};
    const float* g_item[2] = {(const float*)d_in[12], (const float*)d_in[22]};
    const float* b_item[2] = {(const float*)d_in[13], (const float*)d_in[23]};

    auto align = [](size_t x) { return (x + 255) & ~(size_t)255; };
    char* w = (char*)d_ws;
    int* cur_ui = (int*)w;
    int* cur_iu = cur_ui + NN;
    w += align((size_t)2 * NN * 4);
    int* csum_ui = (int*)w; w += align(64 * 4);
    int* csum_iu = (int*)w; w += align(64 * 4);
    int* rp_ui = (int*)w; w += align((size_t)(NN + 1) * 4);
    int* rp_iu = (int*)w; w += align((size_t)(NN + 1) * 4);
    int* csr_ui = (int*)w; w += align((size_t)NE * 4);
    int* csr_iu = (int*)w; w += align((size_t)NE * 4);
    unsigned short* mean_item = (unsigned short*)w; w += align((size_t)NN * CC * 2);
    unsigned short* mean_user = (unsigned short*)w; w += align((size_t)NN * CC * 2);

    float* out_user = (float*)d_out;
    float* out_item = (float*)d_out + (size_t)NN * CC;

    int hb = (NE + 255) / 256;
    int ab = (NN + 7) / 8;

    // ---- CSR build (shared by both layers) ----
    k_zero<<<(2 * NN + 255) / 256, 256, 0, stream>>>(cur_ui, 2 * NN);
    k_hist<<<hb, 256, 0, stream>>>(ei_ui, cur_ui);
    k_hist<<<hb, 256, 0, stream>>>(ei_iu, cur_iu);
    k_scan1<<<NCHUNKS, 256, 0, stream>>>(cur_ui, csum_ui);
    k_scan1<<<NCHUNKS, 256, 0, stream>>>(cur_iu, csum_iu);
    k_scan2<<<2, 1, 0, stream>>>(csum_ui, csum_iu, rp_ui, rp_iu);
    k_scan3<<<NCHUNKS, 256, 0, stream>>>(csum_ui, cur_ui, rp_ui);
    k_scan3<<<NCHUNKS, 256, 0, stream>>>(csum_iu, cur_iu, rp_iu);
    k_fill<<<hb, 256, 0, stream>>>(ei_ui, cur_ui, csr_ui);
    k_fill<<<hb, 256, 0, stream>>>(ei_iu, cur_iu, csr_iu);

    // ---- layer 0 ----
    k_agg<<<ab, 256, 0, stream>>>(x_user, rp_ui, csr_ui, mean_item);
    k_agg<<<ab, 256, 0, stream>>>(x_item, rp_iu, csr_iu, mean_user);
    k_gemm_ln<<<GB, 512, 0, stream>>>(mean_item, x_item, Wl_ui[0], bl_ui[0], Wr_ui[0],
                                      g_item[0], b_item[0], out_item);
    k_gemm_ln<<<GB, 512, 0, stream>>>(mean_user, x_user, Wl_iu[0], bl_iu[0], Wr_iu[0],
                                      g_user[0], b_user[0], out_user);

    // ---- layer 1 (in place on d_out halves; means first) ----
    k_agg<<<ab, 256, 0, stream>>>(out_user, rp_ui, csr_ui, mean_item);
    k_agg<<<ab, 256, 0, stream>>>(out_item, rp_iu, csr_iu, mean_user);
    k_gemm_ln<<<GB, 512, 0, stream>>>(mean_item, out_item, Wl_ui[1], bl_ui[1], Wr_ui[1],
                                      g_item[1], b_item[1], out_item);
    k_gemm_ln<<<GB, 512, 0, stream>>>(mean_user, out_user, Wl_iu[1], bl_iu[1], Wr_iu[1],
                                      g_user[1], b_user[1], out_user);
}

// Round 5
// 488.463 us; speedup vs baseline: 2.9734x; 1.0860x over previous
//
#include <hip/hip_runtime.h>

#define NN 100000
#define NE 600000
#define CC 128
#define NCHUNKS 49           // ceil(NN / 2048)
#define TILE_N 64            // nodes per block in fused SAGE kernel
#define GB2 ((NN + TILE_N - 1) / TILE_N)

typedef __attribute__((ext_vector_type(8))) short short8v;
typedef __attribute__((ext_vector_type(4))) float float4v;
typedef __attribute__((ext_vector_type(4))) unsigned short ushort4v;

__device__ __forceinline__ unsigned short f2bf(float f) {
    union { float f; unsigned u; } c; c.f = f;
    unsigned r = c.u + 0x7FFFu + ((c.u >> 16) & 1u);   // RNE
    return (unsigned short)(r >> 16);
}
__device__ __forceinline__ float bf2f(unsigned short u) {
    union { unsigned u; float f; } c; c.u = (unsigned)u << 16;
    return c.f;
}
__device__ __forceinline__ void acc4(float4& a, float4 v) {
    a.x += v.x; a.y += v.y; a.z += v.z; a.w += v.w;
}
__device__ __forceinline__ void accb(float4& a, ushort4v u) {
    a.x += bf2f(u.x); a.y += bf2f(u.y); a.z += bf2f(u.z); a.w += bf2f(u.w);
}

// ---------------- CSR build (both graphs per launch) ----------------

__global__ void k_zero(int* __restrict__ p, int n) {
    int i = blockIdx.x * blockDim.x + threadIdx.x;
    if (i < n) p[i] = 0;
}

__global__ void k_hist2(const int* __restrict__ ei0, const int* __restrict__ ei1,
                        int* __restrict__ cnt0, int* __restrict__ cnt1, int hb) {
    int bid = blockIdx.x;
    const int* ei = (bid < hb) ? ei0 : ei1;
    int* cnt = (bid < hb) ? cnt0 : cnt1;
    int local = (bid < hb) ? bid : bid - hb;
    int e = local * 256 + threadIdx.x;
    if (e < NE) atomicAdd(&cnt[ei[NE + e]], 1);
}

__global__ void k_scan1(const int* __restrict__ deg0, const int* __restrict__ deg1,
                        int* __restrict__ csum0, int* __restrict__ csum1) {
    __shared__ int s[256];
    int gr = blockIdx.x / NCHUNKS, c = blockIdx.x % NCHUNKS, t = threadIdx.x;
    const int* deg = gr ? deg1 : deg0;
    int* csum = gr ? csum1 : csum0;
    int base = c * 2048 + t * 8;
    int v = 0;
#pragma unroll
    for (int u = 0; u < 8; ++u) { int i = base + u; if (i < NN) v += deg[i]; }
    s[t] = v; __syncthreads();
    for (int off = 128; off > 0; off >>= 1) {
        if (t < off) s[t] += s[t + off];
        __syncthreads();
    }
    if (t == 0) csum[c] = s[0];
}

__global__ void k_scan2(int* __restrict__ csum_ui, int* __restrict__ csum_iu,
                        int* __restrict__ rp_ui, int* __restrict__ rp_iu) {
    int* cs = blockIdx.x ? csum_iu : csum_ui;
    int* rp = blockIdx.x ? rp_iu : rp_ui;
    int run = 0;
    for (int i = 0; i < NCHUNKS; ++i) { int v = cs[i]; cs[i] = run; run += v; }
    rp[NN] = run;
}

__global__ void k_scan3(const int* __restrict__ csum0, const int* __restrict__ csum1,
                        int* __restrict__ dc0, int* __restrict__ dc1,
                        int* __restrict__ rp0, int* __restrict__ rp1) {
    __shared__ int s[256];
    int gr = blockIdx.x / NCHUNKS, c = blockIdx.x % NCHUNKS, t = threadIdx.x;
    const int* csum = gr ? csum1 : csum0;
    int* degcur = gr ? dc1 : dc0;
    int* rp = gr ? rp1 : rp0;
    int base = c * 2048 + t * 8;
    int loc[8]; int v = 0;
#pragma unroll
    for (int u = 0; u < 8; ++u) { int i = base + u; loc[u] = (i < NN) ? degcur[i] : 0; v += loc[u]; }
    s[t] = v; __syncthreads();
    for (int off = 1; off < 256; off <<= 1) {
        int x = (t >= off) ? s[t - off] : 0;
        __syncthreads();
        s[t] += x;
        __syncthreads();
    }
    int pre = s[t] - v + csum[c];
#pragma unroll
    for (int u = 0; u < 8; ++u) {
        int i = base + u;
        if (i < NN) { rp[i] = pre; degcur[i] = pre; pre += loc[u]; }
    }
}

__global__ void k_fill2(const int* __restrict__ ei0, const int* __restrict__ ei1,
                        int* __restrict__ cur0, int* __restrict__ cur1,
                        int* __restrict__ csr0, int* __restrict__ csr1, int hb) {
    int bid = blockIdx.x;
    const int* ei = (bid < hb) ? ei0 : ei1;
    int* cur = (bid < hb) ? cur0 : cur1;
    int* csr = (bid < hb) ? csr0 : csr1;
    int local = (bid < hb) ? bid : bid - hb;
    int e = local * 256 + threadIdx.x;
    if (e < NE) {
        int src = ei[e], dst = ei[NE + e];
        int pos = atomicAdd(&cur[dst], 1);
        csr[pos] = src;
    }
}

// -------- fused SAGE: gather-mean -> [mean|x] @ W^T + b -> LN -> ReLU --------
// 256 thr = 4 waves. Tile: 64 nodes x 128 cols, K=256.
// Gather phase: 8 groups of 32 lanes, each group computes one node's mean at a
// time (4-way unrolled for MLP), bf16 result written straight into the
// XOR-swizzled LDS A-tile. xdst staged into the other K-half. Then 4 waves
// (1 m-group x 4 n-groups) run the MFMA tile, epilogue LN via LDS transpose.
// L1=false: xsrc/xdst fp32, out bf16 (ws).  L1=true: xsrc/xdst bf16, out fp32.

template<bool L1>
__global__ __launch_bounds__(256, 4)
void k_sage(const void* __restrict__ xsrc_, const int* __restrict__ rp,
            const int* __restrict__ csr, const void* __restrict__ xdst_,
            const float* __restrict__ Wl, const float* __restrict__ bl,
            const float* __restrict__ Wr, const float* __restrict__ g,
            const float* __restrict__ bb, void* __restrict__ out_) {
    __shared__ char sA[TILE_N * 512];          // 32 KB bf16 A tile, then fp32 LN buf
    __shared__ float sbl[128], sg[128], sb[128];

    int t = threadIdx.x;
    int base = blockIdx.x * TILE_N;
    if (t < 128) { sbl[t] = bl[t]; sg[t] = g[t]; sb[t] = bb[t]; }

    const float* xsF = (const float*)xsrc_;
    const unsigned short* xsB = (const unsigned short*)xsrc_;

    // ---- gather + mean -> LDS mean half (cols 0..127) ----
    {
        int gi = t >> 5, jl = t & 31, j0 = jl * 4;
#pragma unroll 1
        for (int i = 0; i < 8; ++i) {
            int r = gi * 8 + i;
            int node = base + r;
            float4 a0 = make_float4(0.f, 0.f, 0.f, 0.f);
            float4 a1 = a0, a2 = a0, a3 = a0;
            float inv = 0.f;
            if (node < NN) {
                int b = rp[node], e = rp[node + 1];
                int i2 = b;
                for (; i2 + 4 <= e; i2 += 4) {
                    int s0 = csr[i2], s1 = csr[i2 + 1], s2 = csr[i2 + 2], s3 = csr[i2 + 3];
                    if (L1) {
                        ushort4v u0 = *reinterpret_cast<const ushort4v*>(xsB + (size_t)s0 * CC + j0);
                        ushort4v u1 = *reinterpret_cast<const ushort4v*>(xsB + (size_t)s1 * CC + j0);
                        ushort4v u2 = *reinterpret_cast<const ushort4v*>(xsB + (size_t)s2 * CC + j0);
                        ushort4v u3 = *reinterpret_cast<const ushort4v*>(xsB + (size_t)s3 * CC + j0);
                        accb(a0, u0); accb(a1, u1); accb(a2, u2); accb(a3, u3);
                    } else {
                        float4 v0 = *reinterpret_cast<const float4*>(xsF + (size_t)s0 * CC + j0);
                        float4 v1 = *reinterpret_cast<const float4*>(xsF + (size_t)s1 * CC + j0);
                        float4 v2 = *reinterpret_cast<const float4*>(xsF + (size_t)s2 * CC + j0);
                        float4 v3 = *reinterpret_cast<const float4*>(xsF + (size_t)s3 * CC + j0);
                        acc4(a0, v0); acc4(a1, v1); acc4(a2, v2); acc4(a3, v3);
                    }
                }
                for (; i2 + 2 <= e; i2 += 2) {
                    int s0 = csr[i2], s1 = csr[i2 + 1];
                    if (L1) {
                        accb(a0, *reinterpret_cast<const ushort4v*>(xsB + (size_t)s0 * CC + j0));
                        accb(a1, *reinterpret_cast<const ushort4v*>(xsB + (size_t)s1 * CC + j0));
                    } else {
                        acc4(a0, *reinterpret_cast<const float4*>(xsF + (size_t)s0 * CC + j0));
                        acc4(a1, *reinterpret_cast<const float4*>(xsF + (size_t)s1 * CC + j0));
                    }
                }
                if (i2 < e) {
                    int s0 = csr[i2];
                    if (L1) accb(a0, *reinterpret_cast<const ushort4v*>(xsB + (size_t)s0 * CC + j0));
                    else    acc4(a0, *reinterpret_cast<const float4*>(xsF + (size_t)s0 * CC + j0));
                }
                int deg = e - b;
                inv = 1.f / (float)(deg > 1 ? deg : 1);
            }
            float mx = ((a0.x + a1.x) + (a2.x + a3.x)) * inv;
            float my = ((a0.y + a1.y) + (a2.y + a3.y)) * inv;
            float mz = ((a0.z + a1.z) + (a2.z + a3.z)) * inv;
            float mw = ((a0.w + a1.w) + (a2.w + a3.w)) * inv;
            ushort4v h; h.x = f2bf(mx); h.y = f2bf(my); h.z = f2bf(mz); h.w = f2bf(mw);
            int byte = (r * 512 + jl * 8) ^ ((r & 7) << 4);
            *reinterpret_cast<ushort4v*>(sA + byte) = h;
        }
    }

    // ---- stage xdst half (cols 128..255) ----
    {
        int r = t >> 2, q = t & 3;
        int node = base + r;
        bool valid = node < NN;
#pragma unroll
        for (int u = 0; u < 8; ++u) {
            int c = q * 4 + u * 16;
            ushort4v h2;
            if (L1) {
                h2 = valid ? *reinterpret_cast<const ushort4v*>(
                                 (const unsigned short*)xdst_ + (size_t)node * CC + c)
                           : (ushort4v){0, 0, 0, 0};
            } else {
                float4 f2 = valid ? *reinterpret_cast<const float4*>(
                                        (const float*)xdst_ + (size_t)node * CC + c)
                                  : make_float4(0.f, 0.f, 0.f, 0.f);
                h2.x = f2bf(f2.x); h2.y = f2bf(f2.y); h2.z = f2bf(f2.z); h2.w = f2bf(f2.w);
            }
            int byte2 = (r * 512 + 256 + c * 2) ^ ((r & 7) << 4);
            *reinterpret_cast<ushort4v*>(sA + byte2) = h2;
        }
    }
    __syncthreads();

    // ---- MFMA: 4 waves = 4 n-groups, each 64 rows x 32 cols ----
    int wid = t >> 6, l = t & 63;
    int ng = wid;
    int l15 = l & 15, l4 = l >> 4;

    float4v acc[4][2];
#pragma unroll
    for (int mt = 0; mt < 4; ++mt)
#pragma unroll
        for (int nt = 0; nt < 2; ++nt)
            acc[mt][nt] = (float4v){0.f, 0.f, 0.f, 0.f};

#pragma unroll
    for (int khalf = 0; khalf < 2; ++khalf) {
        const float* Wsrc = khalf ? Wr : Wl;
        short8v bfrag[2][4];
#pragma unroll
        for (int nt = 0; nt < 2; ++nt) {
            int j = ng * 32 + nt * 16 + l15;
            const float* wr_ = Wsrc + (size_t)j * CC + l4 * 8;
#pragma unroll
            for (int kk4 = 0; kk4 < 4; ++kk4) {
                float4 a = *reinterpret_cast<const float4*>(wr_ + kk4 * 32);
                float4 b2 = *reinterpret_cast<const float4*>(wr_ + kk4 * 32 + 4);
                short8v h;
                h[0] = (short)f2bf(a.x);  h[1] = (short)f2bf(a.y);
                h[2] = (short)f2bf(a.z);  h[3] = (short)f2bf(a.w);
                h[4] = (short)f2bf(b2.x); h[5] = (short)f2bf(b2.y);
                h[6] = (short)f2bf(b2.z); h[7] = (short)f2bf(b2.w);
                bfrag[nt][kk4] = h;
            }
        }
#pragma unroll
        for (int kk4 = 0; kk4 < 4; ++kk4) {
            short8v af[4];
#pragma unroll
            for (int mt = 0; mt < 4; ++mt) {
                int row = mt * 16 + l15;
                int byte = (row * 512 + l4 * 16 + (khalf * 4 + kk4) * 64) ^ ((row & 7) << 4);
                af[mt] = *reinterpret_cast<short8v*>(sA + byte);
            }
#pragma unroll
            for (int mt = 0; mt < 4; ++mt)
#pragma unroll
                for (int nt = 0; nt < 2; ++nt)
                    acc[mt][nt] = __builtin_amdgcn_mfma_f32_16x16x32_bf16(
                        af[mt], bfrag[nt][kk4], acc[mt][nt], 0, 0, 0);
        }
    }
    __syncthreads();   // A tile free; reuse as fp32 LN buffer

    // ---- scatter biased acc -> LDS fp32 (same swizzle) ----
#pragma unroll
    for (int mt = 0; mt < 4; ++mt)
#pragma unroll
        for (int r4 = 0; r4 < 4; ++r4) {
            int nrow = mt * 16 + l4 * 4 + r4;
#pragma unroll
            for (int nt = 0; nt < 2; ++nt) {
                int col = ng * 32 + nt * 16 + l15;
                float v = acc[mt][nt][r4] + sbl[col];
                int byte = (nrow * 512 + col * 4) ^ ((nrow & 7) << 4);
                *reinterpret_cast<float*>(sA + byte) = v;
            }
        }
    __syncthreads();

    // ---- transposed LN + ReLU + store ----
    {
        int nn_ = t >> 2, qq = t & 3;
        int gnode = base + nn_;
        float s1 = 0.f, s2 = 0.f;
        float4 vv[8];
#pragma unroll
        for (int u = 0; u < 8; ++u) {
            int c = qq * 4 + u * 16;
            int byte = (nn_ * 512 + c * 4) ^ ((nn_ & 7) << 4);
            float4 vx = *reinterpret_cast<float4*>(sA + byte);
            vv[u] = vx;
            s1 += vx.x + vx.y + vx.z + vx.w;
            s2 += vx.x * vx.x + vx.y * vx.y + vx.z * vx.z + vx.w * vx.w;
        }
        s1 += __shfl_xor(s1, 1); s1 += __shfl_xor(s1, 2);
        s2 += __shfl_xor(s2, 1); s2 += __shfl_xor(s2, 2);
        float mu = s1 * (1.f / 128.f);
        float var = s2 * (1.f / 128.f) - mu * mu;
        float rstd = rsqrtf(var + 1e-5f);
        if (gnode < NN) {
#pragma unroll
            for (int u = 0; u < 8; ++u) {
                int c = qq * 4 + u * 16;
                float4 vx = vv[u];
                float4 o;
                o.x = fmaxf(0.f, (vx.x - mu) * rstd * sg[c + 0] + sb[c + 0]);
                o.y = fmaxf(0.f, (vx.y - mu) * rstd * sg[c + 1] + sb[c + 1]);
                o.z = fmaxf(0.f, (vx.z - mu) * rstd * sg[c + 2] + sb[c + 2]);
                o.w = fmaxf(0.f, (vx.w - mu) * rstd * sg[c + 3] + sb[c + 3]);
                if (L1) {
                    float* op = (float*)out_ + (size_t)gnode * CC;
                    *reinterpret_cast<float4*>(op + c) = o;
                } else {
                    unsigned short* op = (unsigned short*)out_ + (size_t)gnode * CC;
                    ushort4v h; h.x = f2bf(o.x); h.y = f2bf(o.y); h.z = f2bf(o.z); h.w = f2bf(o.w);
                    *reinterpret_cast<ushort4v*>(op + c) = h;
                }
            }
        }
    }
}

// ---------------- launch ----------------

extern "C" void kernel_launch(void* const* d_in, const int* in_sizes, int n_in,
                              void* d_out, int out_size, void* d_ws, size_t ws_size,
                              hipStream_t stream) {
    const float* x_user = (const float*)d_in[0];
    const float* x_item = (const float*)d_in[1];
    const int* ei_ui = (const int*)d_in[2];
    const int* ei_iu = (const int*)d_in[3];

    const float* Wl_ui[2] = {(const float*)d_in[4],  (const float*)d_in[14]};
    const float* bl_ui[2] = {(const float*)d_in[5],  (const float*)d_in[15]};
    const float* Wr_ui[2] = {(const float*)d_in[6],  (const float*)d_in[16]};
    const float* Wl_iu[2] = {(const float*)d_in[7],  (const float*)d_in[17]};
    const float* bl_iu[2] = {(const float*)d_in[8],  (const float*)d_in[18]};
    const float* Wr_iu[2] = {(const float*)d_in[9],  (const float*)d_in[19]};
    const float* g_user[2] = {(const float*)d_in[10], (const float*)d_in[20]};
    const float* b_user[2] = {(const float*)d_in[11], (const float*)d_in[21]};
    const float* g_item[2] = {(const float*)d_in[12], (const float*)d_in[22]};
    const float* b_item[2] = {(const float*)d_in[13], (const float*)d_in[23]};

    auto align = [](size_t x) { return (x + 255) & ~(size_t)255; };
    char* w = (char*)d_ws;
    int* cur_ui = (int*)w;
    int* cur_iu = cur_ui + NN;
    w += align((size_t)2 * NN * 4);
    int* csum_ui = (int*)w; w += align(64 * 4);
    int* csum_iu = (int*)w; w += align(64 * 4);
    int* rp_ui = (int*)w; w += align((size_t)(NN + 1) * 4);
    int* rp_iu = (int*)w; w += align((size_t)(NN + 1) * 4);
    int* csr_ui = (int*)w; w += align((size_t)NE * 4);
    int* csr_iu = (int*)w; w += align((size_t)NE * 4);
    unsigned short* w_user = (unsigned short*)w; w += align((size_t)NN * CC * 2);
    unsigned short* w_item = (unsigned short*)w; w += align((size_t)NN * CC * 2);

    float* out_user = (float*)d_out;
    float* out_item = (float*)d_out + (size_t)NN * CC;

    int hb = (NE + 255) / 256;

    // ---- CSR build (shared by both layers) ----
    k_zero<<<(2 * NN + 255) / 256, 256, 0, stream>>>(cur_ui, 2 * NN);
    k_hist2<<<2 * hb, 256, 0, stream>>>(ei_ui, ei_iu, cur_ui, cur_iu, hb);
    k_scan1<<<2 * NCHUNKS, 256, 0, stream>>>(cur_ui, cur_iu, csum_ui, csum_iu);
    k_scan2<<<2, 1, 0, stream>>>(csum_ui, csum_iu, rp_ui, rp_iu);
    k_scan3<<<2 * NCHUNKS, 256, 0, stream>>>(csum_ui, csum_iu, cur_ui, cur_iu, rp_ui, rp_iu);
    k_fill2<<<2 * hb, 256, 0, stream>>>(ei_ui, ei_iu, cur_ui, cur_iu, csr_ui, csr_iu, hb);

    // ---- layer 0: d_in fp32 -> ws bf16 ----
    k_sage<false><<<GB2, 256, 0, stream>>>(x_user, rp_ui, csr_ui, x_item,
                                           Wl_ui[0], bl_ui[0], Wr_ui[0],
                                           g_item[0], b_item[0], w_item);
    k_sage<false><<<GB2, 256, 0, stream>>>(x_item, rp_iu, csr_iu, x_user,
                                           Wl_iu[0], bl_iu[0], Wr_iu[0],
                                           g_user[0], b_user[0], w_user);

    // ---- layer 1: ws bf16 -> d_out fp32 ----
    k_sage<true><<<GB2, 256, 0, stream>>>(w_user, rp_ui, csr_ui, w_item,
                                          Wl_ui[1], bl_ui[1], Wr_ui[1],
                                          g_item[1], b_item[1], out_item);
    k_sage<true><<<GB2, 256, 0, stream>>>(w_item, rp_iu, csr_iu, w_user,
                                          Wl_iu[1], bl_iu[1], Wr_iu[1],
                                          g_user[1], b_user[1], out_user);
}

// Round 6
// 392.656 us; speedup vs baseline: 3.6988x; 1.2440x over previous
//
#include <hip/hip_runtime.h>

#define NN 100000
#define NE 600000
#define CC 128
#define NCHUNKS 49           // ceil(NN / 2048)
#define HB 2344              // ceil(NE / 256)
#define CVB 6250             // NN*CC / 2048
#define AB 6250              // NN / 16 (nodes per agg block = 16)
#define GBD 782              // ceil(NN / 128)

typedef __attribute__((ext_vector_type(8))) short short8v;
typedef __attribute__((ext_vector_type(8))) unsigned short ushort8v;
typedef __attribute__((ext_vector_type(4))) unsigned short ushort4v;
typedef __attribute__((ext_vector_type(4))) float float4v;

__device__ __forceinline__ unsigned short f2bf(float f) {
    union { float f; unsigned u; } c; c.f = f;
    unsigned r = c.u + 0x7FFFu + ((c.u >> 16) & 1u);   // RNE
    return (unsigned short)(r >> 16);
}
__device__ __forceinline__ float bf2f(unsigned short u) {
    union { unsigned u; float f; } c; c.u = (unsigned)u << 16;
    return c.f;
}
__device__ __forceinline__ void addu8(float4& lo, float4& hi, ushort8v u) {
    lo.x += bf2f(u[0]); lo.y += bf2f(u[1]); lo.z += bf2f(u[2]); lo.w += bf2f(u[3]);
    hi.x += bf2f(u[4]); hi.y += bf2f(u[5]); hi.z += bf2f(u[6]); hi.w += bf2f(u[7]);
}
__device__ __forceinline__ ushort8v cvt8(const float* p) {
    float4 a = *reinterpret_cast<const float4*>(p);
    float4 b = *reinterpret_cast<const float4*>(p + 4);
    ushort8v h;
    h[0] = f2bf(a.x); h[1] = f2bf(a.y); h[2] = f2bf(a.z); h[3] = f2bf(a.w);
    h[4] = f2bf(b.x); h[5] = f2bf(b.y); h[6] = f2bf(b.z); h[7] = f2bf(b.w);
    return h;
}

// ---- mega-kernel: histogram (both graphs) + x->bf16 + W->bf16 ----

__global__ __launch_bounds__(256)
void k_pre(const int* __restrict__ ei0, const int* __restrict__ ei1,
           int* __restrict__ cnt0, int* __restrict__ cnt1,
           const float* __restrict__ xu, const float* __restrict__ xi,
           unsigned short* __restrict__ xbu, unsigned short* __restrict__ xbi,
           const float* w0, const float* w1, const float* w2, const float* w3,
           const float* w4, const float* w5, const float* w6, const float* w7,
           unsigned short* __restrict__ Wb) {
    int bid = blockIdx.x, t = threadIdx.x;
    if (bid < 2 * HB) {
        const int* ei = (bid < HB) ? ei0 : ei1;
        int* cnt = (bid < HB) ? cnt0 : cnt1;
        int local = (bid < HB) ? bid : bid - HB;
        int e = local * 256 + t;
        if (e < NE) atomicAdd(&cnt[ei[NE + e]], 1);
        return;
    }
    bid -= 2 * HB;
    if (bid < 2 * CVB) {
        const float* src = (bid < CVB) ? xu : xi;
        unsigned short* dst = (bid < CVB) ? xbu : xbi;
        int local = (bid < CVB) ? bid : bid - CVB;
        size_t idx = (size_t)local * 2048 + t * 8;
        *reinterpret_cast<ushort8v*>(dst + idx) = cvt8(src + idx);
        return;
    }
    bid -= 2 * CVB;
    int m = bid >> 3;
    const float* src = w0;
    if (m == 1) src = w1; else if (m == 2) src = w2; else if (m == 3) src = w3;
    else if (m == 4) src = w4; else if (m == 5) src = w5;
    else if (m == 6) src = w6; else if (m == 7) src = w7;
    size_t idx = (size_t)(bid & 7) * 2048 + t * 8;
    *reinterpret_cast<ushort8v*>(Wb + (size_t)m * 16384 + idx) = cvt8(src + idx);
}

// ---------------- CSR scans / fill ----------------

__global__ void k_zero(int* __restrict__ p, int n) {
    int i = blockIdx.x * blockDim.x + threadIdx.x;
    if (i < n) p[i] = 0;
}

__global__ void k_scan1(const int* __restrict__ deg0, const int* __restrict__ deg1,
                        int* __restrict__ csum0, int* __restrict__ csum1) {
    __shared__ int s[256];
    int gr = blockIdx.x / NCHUNKS, c = blockIdx.x % NCHUNKS, t = threadIdx.x;
    const int* deg = gr ? deg1 : deg0;
    int* csum = gr ? csum1 : csum0;
    int base = c * 2048 + t * 8;
    int v = 0;
#pragma unroll
    for (int u = 0; u < 8; ++u) { int i = base + u; if (i < NN) v += deg[i]; }
    s[t] = v; __syncthreads();
    for (int off = 128; off > 0; off >>= 1) {
        if (t < off) s[t] += s[t + off];
        __syncthreads();
    }
    if (t == 0) csum[c] = s[0];
}

__global__ void k_scan2(int* __restrict__ csum_ui, int* __restrict__ csum_iu,
                        int* __restrict__ rp_ui, int* __restrict__ rp_iu) {
    int* cs = blockIdx.x ? csum_iu : csum_ui;
    int* rp = blockIdx.x ? rp_iu : rp_ui;
    int run = 0;
    for (int i = 0; i < NCHUNKS; ++i) { int v = cs[i]; cs[i] = run; run += v; }
    rp[NN] = run;
}

__global__ void k_scan3(const int* __restrict__ csum0, const int* __restrict__ csum1,
                        int* __restrict__ dc0, int* __restrict__ dc1,
                        int* __restrict__ rp0, int* __restrict__ rp1) {
    __shared__ int s[256];
    int gr = blockIdx.x / NCHUNKS, c = blockIdx.x % NCHUNKS, t = threadIdx.x;
    const int* csum = gr ? csum1 : csum0;
    int* degcur = gr ? dc1 : dc0;
    int* rp = gr ? rp1 : rp0;
    int base = c * 2048 + t * 8;
    int loc[8]; int v = 0;
#pragma unroll
    for (int u = 0; u < 8; ++u) { int i = base + u; loc[u] = (i < NN) ? degcur[i] : 0; v += loc[u]; }
    s[t] = v; __syncthreads();
    for (int off = 1; off < 256; off <<= 1) {
        int x = (t >= off) ? s[t - off] : 0;
        __syncthreads();
        s[t] += x;
        __syncthreads();
    }
    int pre = s[t] - v + csum[c];
#pragma unroll
    for (int u = 0; u < 8; ++u) {
        int i = base + u;
        if (i < NN) { rp[i] = pre; degcur[i] = pre; pre += loc[u]; }
    }
}

__global__ void k_fill2(const int* __restrict__ ei0, const int* __restrict__ ei1,
                        int* __restrict__ cur0, int* __restrict__ cur1,
                        int* __restrict__ csr0, int* __restrict__ csr1) {
    int bid = blockIdx.x;
    const int* ei = (bid < HB) ? ei0 : ei1;
    int* cur = (bid < HB) ? cur0 : cur1;
    int* csr = (bid < HB) ? csr0 : csr1;
    int local = (bid < HB) ? bid : bid - HB;
    int e = local * 256 + threadIdx.x;
    if (e < NE) {
        int src = ei[e], dst = ei[NE + e];
        int pos = atomicAdd(&cur[dst], 1);
        csr[pos] = src;
    }
}

// ------------- aggregation (both directions in one launch), bf16 -------------
// 16 nodes/block, 16 lanes/node; one ushort8 (16B) covers a lane's row slice.
// 4-way neighbor unroll -> 4 independent loads in flight per lane.

__global__ __launch_bounds__(256)
void k_agg2(const unsigned short* __restrict__ s0, const int* __restrict__ rp0,
            const int* __restrict__ csr0, unsigned short* __restrict__ m0,
            const unsigned short* __restrict__ s1, const int* __restrict__ rp1,
            const int* __restrict__ csr1, unsigned short* __restrict__ m1) {
    int bid = blockIdx.x;
    const unsigned short* src; const int* rp; const int* csr; unsigned short* mean;
    if (bid < AB) { src = s0; rp = rp0; csr = csr0; mean = m0; }
    else { bid -= AB; src = s1; rp = rp1; csr = csr1; mean = m1; }
    int t = threadIdx.x;
    int node = bid * 16 + (t >> 4);
    int j0 = (t & 15) * 8;
    int b = rp[node], e = rp[node + 1];
    float4 z = make_float4(0.f, 0.f, 0.f, 0.f);
    float4 l0 = z, h0 = z, l1 = z, h1 = z, l2 = z, h2 = z, l3 = z, h3 = z;
    int i = b;
    for (; i + 4 <= e; i += 4) {
        int a = csr[i], bb = csr[i + 1], c = csr[i + 2], d = csr[i + 3];
        ushort8v u0 = *reinterpret_cast<const ushort8v*>(src + (size_t)a * CC + j0);
        ushort8v u1 = *reinterpret_cast<const ushort8v*>(src + (size_t)bb * CC + j0);
        ushort8v u2 = *reinterpret_cast<const ushort8v*>(src + (size_t)c * CC + j0);
        ushort8v u3 = *reinterpret_cast<const ushort8v*>(src + (size_t)d * CC + j0);
        addu8(l0, h0, u0); addu8(l1, h1, u1); addu8(l2, h2, u2); addu8(l3, h3, u3);
    }
    for (; i + 2 <= e; i += 2) {
        int a = csr[i], bb = csr[i + 1];
        ushort8v u0 = *reinterpret_cast<const ushort8v*>(src + (size_t)a * CC + j0);
        ushort8v u1 = *reinterpret_cast<const ushort8v*>(src + (size_t)bb * CC + j0);
        addu8(l0, h0, u0); addu8(l1, h1, u1);
    }
    if (i < e) {
        int a = csr[i];
        addu8(l0, h0, *reinterpret_cast<const ushort8v*>(src + (size_t)a * CC + j0));
    }
    int deg = e - b;
    float inv = 1.f / (float)(deg > 1 ? deg : 1);
    float m_[8];
    m_[0] = ((l0.x + l1.x) + (l2.x + l3.x)) * inv;
    m_[1] = ((l0.y + l1.y) + (l2.y + l3.y)) * inv;
    m_[2] = ((l0.z + l1.z) + (l2.z + l3.z)) * inv;
    m_[3] = ((l0.w + l1.w) + (l2.w + l3.w)) * inv;
    m_[4] = ((h0.x + h1.x) + (h2.x + h3.x)) * inv;
    m_[5] = ((h0.y + h1.y) + (h2.y + h3.y)) * inv;
    m_[6] = ((h0.z + h1.z) + (h2.z + h3.z)) * inv;
    m_[7] = ((h0.w + h1.w) + (h2.w + h3.w)) * inv;
    ushort8v h;
#pragma unroll
    for (int k = 0; k < 8; ++k) h[k] = f2bf(m_[k]);
    *reinterpret_cast<ushort8v*>(mean + (size_t)node * CC + j0) = h;
}

// ------- MFMA fused GEMM+LN+ReLU, both directions in one launch -------
// 512 thr = 8 waves (2m x 4n). Tile 128 nodes x 128 cols, K=256, all-bf16 A/B.
// A: LDS [128][256] bf16 XOR-swizzled. B: bf16 W global->reg. Epilogue via LDS.

template<bool OUTF32>
__global__ __launch_bounds__(512, 4)
void k_gemm2(const unsigned short* __restrict__ mean0, const unsigned short* __restrict__ x0,
             const unsigned short* __restrict__ wl0, const unsigned short* __restrict__ wr0,
             const float* __restrict__ bl0, const float* __restrict__ g0,
             const float* __restrict__ bb0, void* __restrict__ out0,
             const unsigned short* __restrict__ mean1, const unsigned short* __restrict__ x1,
             const unsigned short* __restrict__ wl1, const unsigned short* __restrict__ wr1,
             const float* __restrict__ bl1, const float* __restrict__ g1,
             const float* __restrict__ bb1, void* __restrict__ out1) {
    __shared__ char sA[128 * 512];              // 64 KB bf16 A tile, then fp32 LN buf
    __shared__ float sbl[128], sg[128], sb[128];

    int bid = blockIdx.x;
    const unsigned short *mean, *xs, *wl, *wr;
    const float *bl, *g, *bb;
    void* out;
    if (bid < GBD) { mean = mean0; xs = x0; wl = wl0; wr = wr0; bl = bl0; g = g0; bb = bb0; out = out0; }
    else { bid -= GBD; mean = mean1; xs = x1; wl = wl1; wr = wr1; bl = bl1; g = g1; bb = bb1; out = out1; }

    int t = threadIdx.x;
    int base = bid * 128;
    if (t < 128) { sbl[t] = bl[t]; sg[t] = g[t]; sb[t] = bb[t]; }

    // ---- stage A tile (both halves bf16) ----
    {
        int r = t >> 2, q = t & 3;
        int swz = (r & 7) << 4;
        int node = base + r;
        bool valid = node < NN;
        const unsigned short* mrow = mean + (size_t)node * CC;
        const unsigned short* xrow = xs + (size_t)node * CC;
        ushort8v zz = (ushort8v){0, 0, 0, 0, 0, 0, 0, 0};
#pragma unroll
        for (int j = 0; j < 4; ++j) {
            int col = (j * 4 + q) * 8;
            ushort8v hm = valid ? *reinterpret_cast<const ushort8v*>(mrow + col) : zz;
            *reinterpret_cast<ushort8v*>(sA + ((r * 512 + col * 2) ^ swz)) = hm;
            ushort8v hx = valid ? *reinterpret_cast<const ushort8v*>(xrow + col) : zz;
            *reinterpret_cast<ushort8v*>(sA + ((r * 512 + 256 + col * 2) ^ swz)) = hx;
        }
    }
    __syncthreads();

    int wid = t >> 6, l = t & 63;
    int mg = wid >> 2, ng = wid & 3;
    int l15 = l & 15, l4 = l >> 4;

    float4v acc[4][2];
#pragma unroll
    for (int mt = 0; mt < 4; ++mt)
#pragma unroll
        for (int nt = 0; nt < 2; ++nt)
            acc[mt][nt] = (float4v){0.f, 0.f, 0.f, 0.f};

#pragma unroll
    for (int khalf = 0; khalf < 2; ++khalf) {
        const unsigned short* Wsrc = khalf ? wr : wl;
        short8v bfrag[2][4];
#pragma unroll
        for (int nt = 0; nt < 2; ++nt) {
            int j = ng * 32 + nt * 16 + l15;
            const unsigned short* wrow = Wsrc + (size_t)j * CC + l4 * 8;
#pragma unroll
            for (int kk4 = 0; kk4 < 4; ++kk4)
                bfrag[nt][kk4] = *reinterpret_cast<const short8v*>(wrow + kk4 * 32);
        }
#pragma unroll
        for (int kk4 = 0; kk4 < 4; ++kk4) {
            short8v af[4];
#pragma unroll
            for (int mt = 0; mt < 4; ++mt) {
                int row = mg * 64 + mt * 16 + l15;
                int byte = (row * 512 + l4 * 16 + (khalf * 4 + kk4) * 64) ^ ((row & 7) << 4);
                af[mt] = *reinterpret_cast<short8v*>(sA + byte);
            }
#pragma unroll
            for (int mt = 0; mt < 4; ++mt)
#pragma unroll
                for (int nt = 0; nt < 2; ++nt)
                    acc[mt][nt] = __builtin_amdgcn_mfma_f32_16x16x32_bf16(
                        af[mt], bfrag[nt][kk4], acc[mt][nt], 0, 0, 0);
        }
    }
    __syncthreads();   // A tile free; reuse as fp32 LN buffer

    // ---- scatter biased acc -> LDS fp32 (same swizzle) ----
#pragma unroll
    for (int mt = 0; mt < 4; ++mt)
#pragma unroll
        for (int r4 = 0; r4 < 4; ++r4) {
            int nrow = mg * 64 + mt * 16 + l4 * 4 + r4;
#pragma unroll
            for (int nt = 0; nt < 2; ++nt) {
                int col = ng * 32 + nt * 16 + l15;
                float v = acc[mt][nt][r4] + sbl[col];
                int byte = (nrow * 512 + col * 4) ^ ((nrow & 7) << 4);
                *reinterpret_cast<float*>(sA + byte) = v;
            }
        }
    __syncthreads();

    // ---- transposed LN + ReLU + store ----
    {
        int nn_ = t >> 2, qq = t & 3;
        int gnode = base + nn_;
        float s1 = 0.f, s2 = 0.f;
        float4 vv[8];
#pragma unroll
        for (int u = 0; u < 8; ++u) {
            int c = qq * 4 + u * 16;
            int byte = (nn_ * 512 + c * 4) ^ ((nn_ & 7) << 4);
            float4 vx = *reinterpret_cast<float4*>(sA + byte);
            vv[u] = vx;
            s1 += vx.x + vx.y + vx.z + vx.w;
            s2 += vx.x * vx.x + vx.y * vx.y + vx.z * vx.z + vx.w * vx.w;
        }
        s1 += __shfl_xor(s1, 1); s1 += __shfl_xor(s1, 2);
        s2 += __shfl_xor(s2, 1); s2 += __shfl_xor(s2, 2);
        float mu = s1 * (1.f / 128.f);
        float var = s2 * (1.f / 128.f) - mu * mu;
        float rstd = rsqrtf(var + 1e-5f);
        if (gnode < NN) {
#pragma unroll
            for (int u = 0; u < 8; ++u) {
                int c = qq * 4 + u * 16;
                float4 vx = vv[u];
                float4 o;
                o.x = fmaxf(0.f, (vx.x - mu) * rstd * sg[c + 0] + sb[c + 0]);
                o.y = fmaxf(0.f, (vx.y - mu) * rstd * sg[c + 1] + sb[c + 1]);
                o.z = fmaxf(0.f, (vx.z - mu) * rstd * sg[c + 2] + sb[c + 2]);
                o.w = fmaxf(0.f, (vx.w - mu) * rstd * sg[c + 3] + sb[c + 3]);
                if (OUTF32) {
                    float* op = (float*)out + (size_t)gnode * CC;
                    *reinterpret_cast<float4*>(op + c) = o;
                } else {
                    unsigned short* op = (unsigned short*)out + (size_t)gnode * CC;
                    ushort4v h; h.x = f2bf(o.x); h.y = f2bf(o.y); h.z = f2bf(o.z); h.w = f2bf(o.w);
                    *reinterpret_cast<ushort4v*>(op + c) = h;
                }
            }
        }
    }
}

// ---------------- launch ----------------

extern "C" void kernel_launch(void* const* d_in, const int* in_sizes, int n_in,
                              void* d_out, int out_size, void* d_ws, size_t ws_size,
                              hipStream_t stream) {
    const float* x_user = (const float*)d_in[0];
    const float* x_item = (const float*)d_in[1];
    const int* ei_ui = (const int*)d_in[2];
    const int* ei_iu = (const int*)d_in[3];

    const float* Wl_ui[2] = {(const float*)d_in[4],  (const float*)d_in[14]};
    const float* bl_ui[2] = {(const float*)d_in[5],  (const float*)d_in[15]};
    const float* Wr_ui[2] = {(const float*)d_in[6],  (const float*)d_in[16]};
    const float* Wl_iu[2] = {(const float*)d_in[7],  (const float*)d_in[17]};
    const float* bl_iu[2] = {(const float*)d_in[8],  (const float*)d_in[18]};
    const float* Wr_iu[2] = {(const float*)d_in[9],  (const float*)d_in[19]};
    const float* g_user[2] = {(const float*)d_in[10], (const float*)d_in[20]};
    const float* b_user[2] = {(const float*)d_in[11], (const float*)d_in[21]};
    const float* g_item[2] = {(const float*)d_in[12], (const float*)d_in[22]};
    const float* b_item[2] = {(const float*)d_in[13], (const float*)d_in[23]};

    auto align = [](size_t x) { return (x + 255) & ~(size_t)255; };
    char* w = (char*)d_ws;
    int* cur_ui = (int*)w;
    int* cur_iu = cur_ui + NN;
    w += align((size_t)2 * NN * 4);
    int* csum_ui = (int*)w; w += align(64 * 4);
    int* csum_iu = (int*)w; w += align(64 * 4);
    int* rp_ui = (int*)w; w += align((size_t)(NN + 1) * 4);
    int* rp_iu = (int*)w; w += align((size_t)(NN + 1) * 4);
    int* csr_ui = (int*)w; w += align((size_t)NE * 4);
    int* csr_iu = (int*)w; w += align((size_t)NE * 4);
    unsigned short* Wb = (unsigned short*)w; w += align((size_t)8 * 16384 * 2);
    unsigned short* xb_user = (unsigned short*)w; w += align((size_t)NN * CC * 2);
    unsigned short* xb_item = (unsigned short*)w; w += align((size_t)NN * CC * 2);
    unsigned short* w_user = (unsigned short*)w; w += align((size_t)NN * CC * 2);
    unsigned short* w_item = (unsigned short*)w; w += align((size_t)NN * CC * 2);
    unsigned short* mean_item = (unsigned short*)w; w += align((size_t)NN * CC * 2);
    unsigned short* mean_user = (unsigned short*)w; w += align((size_t)NN * CC * 2);

    float* out_user = (float*)d_out;
    float* out_item = (float*)d_out + (size_t)NN * CC;

    // ---- CSR build + bf16 conversions ----
    k_zero<<<(2 * NN + 255) / 256, 256, 0, stream>>>(cur_ui, 2 * NN);
    k_pre<<<2 * HB + 2 * CVB + 64, 256, 0, stream>>>(
        ei_ui, ei_iu, cur_ui, cur_iu, x_user, x_item, xb_user, xb_item,
        Wl_ui[0], Wr_ui[0], Wl_iu[0], Wr_iu[0],
        Wl_ui[1], Wr_ui[1], Wl_iu[1], Wr_iu[1], Wb);
    k_scan1<<<2 * NCHUNKS, 256, 0, stream>>>(cur_ui, cur_iu, csum_ui, csum_iu);
    k_scan2<<<2, 1, 0, stream>>>(csum_ui, csum_iu, rp_ui, rp_iu);
    k_scan3<<<2 * NCHUNKS, 256, 0, stream>>>(csum_ui, csum_iu, cur_ui, cur_iu, rp_ui, rp_iu);
    k_fill2<<<2 * HB, 256, 0, stream>>>(ei_ui, ei_iu, cur_ui, cur_iu, csr_ui, csr_iu);

    // ---- layer 0 ----
    k_agg2<<<2 * AB, 256, 0, stream>>>(xb_user, rp_ui, csr_ui, mean_item,
                                       xb_item, rp_iu, csr_iu, mean_user);
    k_gemm2<false><<<2 * GBD, 512, 0, stream>>>(
        mean_item, xb_item, Wb + 0 * 16384, Wb + 1 * 16384,
        bl_ui[0], g_item[0], b_item[0], w_item,
        mean_user, xb_user, Wb + 2 * 16384, Wb + 3 * 16384,
        bl_iu[0], g_user[0], b_user[0], w_user);

    // ---- layer 1 ----
    k_agg2<<<2 * AB, 256, 0, stream>>>(w_user, rp_ui, csr_ui, mean_item,
                                       w_item, rp_iu, csr_iu, mean_user);
    k_gemm2<true><<<2 * GBD, 512, 0, stream>>>(
        mean_item, w_item, Wb + 4 * 16384, Wb + 5 * 16384,
        bl_ui[1], g_item[1], b_item[1], out_item,
        mean_user, w_user, Wb + 6 * 16384, Wb + 7 * 16384,
        bl_iu[1], g_user[1], b_user[1], out_user);
}

// Round 7
// 317.659 us; speedup vs baseline: 4.5721x; 1.2361x over previous
//
#include <hip/hip_runtime.h>

#define NN 100000
#define NE 600000
#define CC 128
#define CVB 6250             // NN*CC / 2048
#define AB 6250              // NN / 16 (nodes per agg block = 16)
#define GBD 782              // ceil(NN / 128)
#define NBK 49               // coarse buckets per graph (dst >> 11)
#define BCAP 16384           // slots per bucket (expected ~12245, 34 sigma margin)
#define EPB 8192             // edges per block in bucket pass
#define BBLK 74              // ceil(NE / EPB)

typedef __attribute__((ext_vector_type(8))) short short8v;
typedef __attribute__((ext_vector_type(8))) unsigned short ushort8v;
typedef __attribute__((ext_vector_type(4))) unsigned short ushort4v;
typedef __attribute__((ext_vector_type(4))) float float4v;

__device__ __forceinline__ unsigned short f2bf(float f) {
    union { float f; unsigned u; } c; c.f = f;
    unsigned r = c.u + 0x7FFFu + ((c.u >> 16) & 1u);   // RNE
    return (unsigned short)(r >> 16);
}
__device__ __forceinline__ float bf2f(unsigned short u) {
    union { unsigned u; float f; } c; c.u = (unsigned)u << 16;
    return c.f;
}
__device__ __forceinline__ void addu8(float4& lo, float4& hi, ushort8v u) {
    lo.x += bf2f(u[0]); lo.y += bf2f(u[1]); lo.z += bf2f(u[2]); lo.w += bf2f(u[3]);
    hi.x += bf2f(u[4]); hi.y += bf2f(u[5]); hi.z += bf2f(u[6]); hi.w += bf2f(u[7]);
}
__device__ __forceinline__ ushort8v cvt8(const float* p) {
    float4 a = *reinterpret_cast<const float4*>(p);
    float4 b = *reinterpret_cast<const float4*>(p + 4);
    ushort8v h;
    h[0] = f2bf(a.x); h[1] = f2bf(a.y); h[2] = f2bf(a.z); h[3] = f2bf(a.w);
    h[4] = f2bf(b.x); h[5] = f2bf(b.y); h[6] = f2bf(b.z); h[7] = f2bf(b.w);
    return h;
}

// ---- k_pre: pure streaming x->bf16 + W->bf16 (+ zero bucket cursors) ----

__global__ __launch_bounds__(256)
void k_pre(const float* __restrict__ xu, const float* __restrict__ xi,
           unsigned short* __restrict__ xbu, unsigned short* __restrict__ xbi,
           const float* w0, const float* w1, const float* w2, const float* w3,
           const float* w4, const float* w5, const float* w6, const float* w7,
           unsigned short* __restrict__ Wb, int* __restrict__ cur) {
    int bid = blockIdx.x, t = threadIdx.x;
    if (bid == 0 && t < 2 * NBK) cur[t] = 0;
    if (bid < 2 * CVB) {
        const float* src = (bid < CVB) ? xu : xi;
        unsigned short* dst = (bid < CVB) ? xbu : xbi;
        int local = (bid < CVB) ? bid : bid - CVB;
        size_t idx = (size_t)local * 2048 + t * 8;
        *reinterpret_cast<ushort8v*>(dst + idx) = cvt8(src + idx);
        return;
    }
    bid -= 2 * CVB;
    int m = bid >> 3;
    const float* src = w0;
    if (m == 1) src = w1; else if (m == 2) src = w2; else if (m == 3) src = w3;
    else if (m == 4) src = w4; else if (m == 5) src = w5;
    else if (m == 6) src = w6; else if (m == 7) src = w7;
    size_t idx = (size_t)(bid & 7) * 2048 + t * 8;
    *reinterpret_cast<ushort8v*>(Wb + (size_t)m * 16384 + idx) = cvt8(src + idx);
}

// ---- k_bucket: multisplit edges into 49 coarse dst-buckets per graph ----
// Per block: LDS hist over 49 bins, one reservation atomic per bin, then
// append (src,dst) pairs into contiguous per-(block,bucket) chunks.

__global__ __launch_bounds__(256)
void k_bucket(const int* __restrict__ ei0, const int* __restrict__ ei1,
              int* __restrict__ cur, int2* __restrict__ bkt) {
    __shared__ int hist[NBK];
    __shared__ int basew[NBK];
    int bid = blockIdx.x;
    int g = (bid >= BBLK) ? 1 : 0;
    const int* ei = g ? ei1 : ei0;
    int local = g ? bid - BBLK : bid;
    int e0 = local * EPB;
    int cnt = NE - e0; if (cnt > EPB) cnt = EPB;
    int t = threadIdx.x;
    if (t < NBK) hist[t] = 0;
    __syncthreads();
    for (int i = t; i < cnt; i += 256)
        atomicAdd(&hist[ei[NE + e0 + i] >> 11], 1);
    __syncthreads();
    if (t < NBK) {
        basew[t] = atomicAdd(&cur[g * NBK + t], hist[t]);
        hist[t] = 0;                        // reuse as local rank cursor
    }
    __syncthreads();
    int2* bg = bkt + (size_t)g * NBK * BCAP;
    for (int i = t; i < cnt; i += 256) {
        int dst = ei[NE + e0 + i];
        int src = ei[e0 + i];
        int b = dst >> 11;
        int r = atomicAdd(&hist[b], 1);
        int pos = basew[b] + r;
        if (pos < BCAP)                     // statistical impossibility guard
            bg[(size_t)b * BCAP + pos] = make_int2(src, dst);
    }
}

// ---- k_csr: per-bucket counting sort -> padded CSR + rp/re ----
// One block per (graph, bucket): LDS degree count over 2048 dsts, LDS scan,
// LDS-cursor scatter. csr writes land in a 64KB L2-resident window.

__global__ __launch_bounds__(256)
void k_csr(const int* __restrict__ cnts, const int2* __restrict__ bkt,
           int* __restrict__ rp0, int* __restrict__ re0,
           int* __restrict__ rp1, int* __restrict__ re1,
           int* __restrict__ csr) {
    __shared__ int deg[2048];
    __shared__ int curp[2048];
    __shared__ int s[256];
    int bid = blockIdx.x;
    int g = (bid >= NBK) ? 1 : 0;
    int bb = g ? bid - NBK : bid;
    int t = threadIdx.x;
    const int2* eb = bkt + (size_t)(g * NBK + bb) * BCAP;
    int cnt = cnts[g * NBK + bb];
    if (cnt > BCAP) cnt = BCAP;
    int dbase = bb * 2048;
    int cb = (g * NBK + bb) * BCAP;
    int* rp = g ? rp1 : rp0;
    int* re = g ? re1 : re0;
    for (int i = t; i < 2048; i += 256) deg[i] = 0;
    __syncthreads();
    for (int i = t; i < cnt; i += 256) {
        int2 e = eb[i];
        atomicAdd(&deg[e.y - dbase], 1);
    }
    __syncthreads();
    int loc[8]; int v = 0; int b8 = t * 8;
#pragma unroll
    for (int u = 0; u < 8; ++u) { loc[u] = deg[b8 + u]; v += loc[u]; }
    s[t] = v; __syncthreads();
    for (int off = 1; off < 256; off <<= 1) {
        int x = (t >= off) ? s[t - off] : 0;
        __syncthreads();
        s[t] += x;
        __syncthreads();
    }
    int run = s[t] - v;
#pragma unroll
    for (int u = 0; u < 8; ++u) {
        int d = b8 + u;
        int gd = dbase + d;
        int start = cb + run;
        curp[d] = start;
        if (gd < NN) { rp[gd] = start; re[gd] = start + loc[u]; }
        run += loc[u];
    }
    __syncthreads();
    for (int i = t; i < cnt; i += 256) {
        int2 e = eb[i];
        int p = atomicAdd(&curp[e.y - dbase], 1);
        csr[p] = e.x;
    }
}

// ------------- aggregation (both directions in one launch), bf16 -------------
// 16 nodes/block, 16 lanes/node; one ushort8 (16B) covers a lane's row slice.
// 4-way neighbor unroll -> 4 independent loads in flight per lane.

__global__ __launch_bounds__(256)
void k_agg2(const unsigned short* __restrict__ s0, const int* __restrict__ rp0,
            const int* __restrict__ re0, unsigned short* __restrict__ m0,
            const unsigned short* __restrict__ s1, const int* __restrict__ rp1,
            const int* __restrict__ re1, unsigned short* __restrict__ m1,
            const int* __restrict__ csr) {
    int bid = blockIdx.x;
    const unsigned short* src; const int* rp; const int* re; unsigned short* mean;
    if (bid < AB) { src = s0; rp = rp0; re = re0; mean = m0; }
    else { bid -= AB; src = s1; rp = rp1; re = re1; mean = m1; }
    int t = threadIdx.x;
    int node = bid * 16 + (t >> 4);
    int j0 = (t & 15) * 8;
    int b = rp[node], e = re[node];
    float4 z = make_float4(0.f, 0.f, 0.f, 0.f);
    float4 l0 = z, h0 = z, l1 = z, h1 = z, l2 = z, h2 = z, l3 = z, h3 = z;
    int i = b;
    for (; i + 4 <= e; i += 4) {
        int a = csr[i], bb = csr[i + 1], c = csr[i + 2], d = csr[i + 3];
        ushort8v u0 = *reinterpret_cast<const ushort8v*>(src + (size_t)a * CC + j0);
        ushort8v u1 = *reinterpret_cast<const ushort8v*>(src + (size_t)bb * CC + j0);
        ushort8v u2 = *reinterpret_cast<const ushort8v*>(src + (size_t)c * CC + j0);
        ushort8v u3 = *reinterpret_cast<const ushort8v*>(src + (size_t)d * CC + j0);
        addu8(l0, h0, u0); addu8(l1, h1, u1); addu8(l2, h2, u2); addu8(l3, h3, u3);
    }
    for (; i + 2 <= e; i += 2) {
        int a = csr[i], bb = csr[i + 1];
        ushort8v u0 = *reinterpret_cast<const ushort8v*>(src + (size_t)a * CC + j0);
        ushort8v u1 = *reinterpret_cast<const ushort8v*>(src + (size_t)bb * CC + j0);
        addu8(l0, h0, u0); addu8(l1, h1, u1);
    }
    if (i < e) {
        int a = csr[i];
        addu8(l0, h0, *reinterpret_cast<const ushort8v*>(src + (size_t)a * CC + j0));
    }
    int dg = e - b;
    float inv = 1.f / (float)(dg > 1 ? dg : 1);
    float m_[8];
    m_[0] = ((l0.x + l1.x) + (l2.x + l3.x)) * inv;
    m_[1] = ((l0.y + l1.y) + (l2.y + l3.y)) * inv;
    m_[2] = ((l0.z + l1.z) + (l2.z + l3.z)) * inv;
    m_[3] = ((l0.w + l1.w) + (l2.w + l3.w)) * inv;
    m_[4] = ((h0.x + h1.x) + (h2.x + h3.x)) * inv;
    m_[5] = ((h0.y + h1.y) + (h2.y + h3.y)) * inv;
    m_[6] = ((h0.z + h1.z) + (h2.z + h3.z)) * inv;
    m_[7] = ((h0.w + h1.w) + (h2.w + h3.w)) * inv;
    ushort8v h;
#pragma unroll
    for (int k = 0; k < 8; ++k) h[k] = f2bf(m_[k]);
    *reinterpret_cast<ushort8v*>(mean + (size_t)node * CC + j0) = h;
}

// ------- MFMA fused GEMM+LN+ReLU, both directions in one launch -------
// 512 thr = 8 waves (2m x 4n). Tile 128 nodes x 128 cols, K=256, all-bf16 A/B.
// A: LDS [128][256] bf16 XOR-swizzled. B: bf16 W global->reg. Epilogue via LDS.

template<bool OUTF32>
__global__ __launch_bounds__(512, 4)
void k_gemm2(const unsigned short* __restrict__ mean0, const unsigned short* __restrict__ x0,
             const unsigned short* __restrict__ wl0, const unsigned short* __restrict__ wr0,
             const float* __restrict__ bl0, const float* __restrict__ g0,
             const float* __restrict__ bb0, void* __restrict__ out0,
             const unsigned short* __restrict__ mean1, const unsigned short* __restrict__ x1,
             const unsigned short* __restrict__ wl1, const unsigned short* __restrict__ wr1,
             const float* __restrict__ bl1, const float* __restrict__ g1,
             const float* __restrict__ bb1, void* __restrict__ out1) {
    __shared__ char sA[128 * 512];              // 64 KB bf16 A tile, then fp32 LN buf
    __shared__ float sbl[128], sg[128], sb[128];

    int bid = blockIdx.x;
    const unsigned short *mean, *xs, *wl, *wr;
    const float *bl, *g, *bb;
    void* out;
    if (bid < GBD) { mean = mean0; xs = x0; wl = wl0; wr = wr0; bl = bl0; g = g0; bb = bb0; out = out0; }
    else { bid -= GBD; mean = mean1; xs = x1; wl = wl1; wr = wr1; bl = bl1; g = g1; bb = bb1; out = out1; }

    int t = threadIdx.x;
    int base = bid * 128;
    if (t < 128) { sbl[t] = bl[t]; sg[t] = g[t]; sb[t] = bb[t]; }

    // ---- stage A tile (both halves bf16) ----
    {
        int r = t >> 2, q = t & 3;
        int swz = (r & 7) << 4;
        int node = base + r;
        bool valid = node < NN;
        const unsigned short* mrow = mean + (size_t)node * CC;
        const unsigned short* xrow = xs + (size_t)node * CC;
        ushort8v zz = (ushort8v){0, 0, 0, 0, 0, 0, 0, 0};
#pragma unroll
        for (int j = 0; j < 4; ++j) {
            int col = (j * 4 + q) * 8;
            ushort8v hm = valid ? *reinterpret_cast<const ushort8v*>(mrow + col) : zz;
            *reinterpret_cast<ushort8v*>(sA + ((r * 512 + col * 2) ^ swz)) = hm;
            ushort8v hx = valid ? *reinterpret_cast<const ushort8v*>(xrow + col) : zz;
            *reinterpret_cast<ushort8v*>(sA + ((r * 512 + 256 + col * 2) ^ swz)) = hx;
        }
    }
    __syncthreads();

    int wid = t >> 6, l = t & 63;
    int mg = wid >> 2, ng = wid & 3;
    int l15 = l & 15, l4 = l >> 4;

    float4v acc[4][2];
#pragma unroll
    for (int mt = 0; mt < 4; ++mt)
#pragma unroll
        for (int nt = 0; nt < 2; ++nt)
            acc[mt][nt] = (float4v){0.f, 0.f, 0.f, 0.f};

#pragma unroll
    for (int khalf = 0; khalf < 2; ++khalf) {
        const unsigned short* Wsrc = khalf ? wr : wl;
        short8v bfrag[2][4];
#pragma unroll
        for (int nt = 0; nt < 2; ++nt) {
            int j = ng * 32 + nt * 16 + l15;
            const unsigned short* wrow = Wsrc + (size_t)j * CC + l4 * 8;
#pragma unroll
            for (int kk4 = 0; kk4 < 4; ++kk4)
                bfrag[nt][kk4] = *reinterpret_cast<const short8v*>(wrow + kk4 * 32);
        }
#pragma unroll
        for (int kk4 = 0; kk4 < 4; ++kk4) {
            short8v af[4];
#pragma unroll
            for (int mt = 0; mt < 4; ++mt) {
                int row = mg * 64 + mt * 16 + l15;
                int byte = (row * 512 + l4 * 16 + (khalf * 4 + kk4) * 64) ^ ((row & 7) << 4);
                af[mt] = *reinterpret_cast<short8v*>(sA + byte);
            }
#pragma unroll
            for (int mt = 0; mt < 4; ++mt)
#pragma unroll
                for (int nt = 0; nt < 2; ++nt)
                    acc[mt][nt] = __builtin_amdgcn_mfma_f32_16x16x32_bf16(
                        af[mt], bfrag[nt][kk4], acc[mt][nt], 0, 0, 0);
        }
    }
    __syncthreads();   // A tile free; reuse as fp32 LN buffer

    // ---- scatter biased acc -> LDS fp32 (same swizzle) ----
#pragma unroll
    for (int mt = 0; mt < 4; ++mt)
#pragma unroll
        for (int r4 = 0; r4 < 4; ++r4) {
            int nrow = mg * 64 + mt * 16 + l4 * 4 + r4;
#pragma unroll
            for (int nt = 0; nt < 2; ++nt) {
                int col = ng * 32 + nt * 16 + l15;
                float v = acc[mt][nt][r4] + sbl[col];
                int byte = (nrow * 512 + col * 4) ^ ((nrow & 7) << 4);
                *reinterpret_cast<float*>(sA + byte) = v;
            }
        }
    __syncthreads();

    // ---- transposed LN + ReLU + store ----
    {
        int nn_ = t >> 2, qq = t & 3;
        int gnode = base + nn_;
        float s1 = 0.f, s2 = 0.f;
        float4 vv[8];
#pragma unroll
        for (int u = 0; u < 8; ++u) {
            int c = qq * 4 + u * 16;
            int byte = (nn_ * 512 + c * 4) ^ ((nn_ & 7) << 4);
            float4 vx = *reinterpret_cast<float4*>(sA + byte);
            vv[u] = vx;
            s1 += vx.x + vx.y + vx.z + vx.w;
            s2 += vx.x * vx.x + vx.y * vx.y + vx.z * vx.z + vx.w * vx.w;
        }
        s1 += __shfl_xor(s1, 1); s1 += __shfl_xor(s1, 2);
        s2 += __shfl_xor(s2, 1); s2 += __shfl_xor(s2, 2);
        float mu = s1 * (1.f / 128.f);
        float var = s2 * (1.f / 128.f) - mu * mu;
        float rstd = rsqrtf(var + 1e-5f);
        if (gnode < NN) {
#pragma unroll
            for (int u = 0; u < 8; ++u) {
                int c = qq * 4 + u * 16;
                float4 vx = vv[u];
                float4 o;
                o.x = fmaxf(0.f, (vx.x - mu) * rstd * sg[c + 0] + sb[c + 0]);
                o.y = fmaxf(0.f, (vx.y - mu) * rstd * sg[c + 1] + sb[c + 1]);
                o.z = fmaxf(0.f, (vx.z - mu) * rstd * sg[c + 2] + sb[c + 2]);
                o.w = fmaxf(0.f, (vx.w - mu) * rstd * sg[c + 3] + sb[c + 3]);
                if (OUTF32) {
                    float* op = (float*)out + (size_t)gnode * CC;
                    *reinterpret_cast<float4*>(op + c) = o;
                } else {
                    unsigned short* op = (unsigned short*)out + (size_t)gnode * CC;
                    ushort4v h; h.x = f2bf(o.x); h.y = f2bf(o.y); h.z = f2bf(o.z); h.w = f2bf(o.w);
                    *reinterpret_cast<ushort4v*>(op + c) = h;
                }
            }
        }
    }
}

// ---------------- launch ----------------

extern "C" void kernel_launch(void* const* d_in, const int* in_sizes, int n_in,
                              void* d_out, int out_size, void* d_ws, size_t ws_size,
                              hipStream_t stream) {
    const float* x_user = (const float*)d_in[0];
    const float* x_item = (const float*)d_in[1];
    const int* ei_ui = (const int*)d_in[2];
    const int* ei_iu = (const int*)d_in[3];

    const float* Wl_ui[2] = {(const float*)d_in[4],  (const float*)d_in[14]};
    const float* bl_ui[2] = {(const float*)d_in[5],  (const float*)d_in[15]};
    const float* Wr_ui[2] = {(const float*)d_in[6],  (const float*)d_in[16]};
    const float* Wl_iu[2] = {(const float*)d_in[7],  (const float*)d_in[17]};
    const float* bl_iu[2] = {(const float*)d_in[8],  (const float*)d_in[18]};
    const float* Wr_iu[2] = {(const float*)d_in[9],  (const float*)d_in[19]};
    const float* g_user[2] = {(const float*)d_in[10], (const float*)d_in[20]};
    const float* b_user[2] = {(const float*)d_in[11], (const float*)d_in[21]};
    const float* g_item[2] = {(const float*)d_in[12], (const float*)d_in[22]};
    const float* b_item[2] = {(const float*)d_in[13], (const float*)d_in[23]};

    auto align = [](size_t x) { return (x + 255) & ~(size_t)255; };
    char* w = (char*)d_ws;
    int* cur = (int*)w; w += align((size_t)2 * NBK * 4);
    int2* bkt = (int2*)w; w += align((size_t)2 * NBK * BCAP * 8);
    int* csr = (int*)w; w += align((size_t)2 * NBK * BCAP * 4);
    int* rp_ui = (int*)w; w += align((size_t)NN * 4);
    int* re_ui = (int*)w; w += align((size_t)NN * 4);
    int* rp_iu = (int*)w; w += align((size_t)NN * 4);
    int* re_iu = (int*)w; w += align((size_t)NN * 4);
    unsigned short* Wb = (unsigned short*)w; w += align((size_t)8 * 16384 * 2);
    unsigned short* xb_user = (unsigned short*)w; w += align((size_t)NN * CC * 2);
    unsigned short* xb_item = (unsigned short*)w; w += align((size_t)NN * CC * 2);
    unsigned short* w_user = (unsigned short*)w; w += align((size_t)NN * CC * 2);
    unsigned short* w_item = (unsigned short*)w; w += align((size_t)NN * CC * 2);
    unsigned short* mean_item = (unsigned short*)w; w += align((size_t)NN * CC * 2);
    unsigned short* mean_user = (unsigned short*)w; w += align((size_t)NN * CC * 2);

    float* out_user = (float*)d_out;
    float* out_item = (float*)d_out + (size_t)NN * CC;

    // ---- conversions (+ zero bucket cursors) ----
    k_pre<<<2 * CVB + 64, 256, 0, stream>>>(
        x_user, x_item, xb_user, xb_item,
        Wl_ui[0], Wr_ui[0], Wl_iu[0], Wr_iu[0],
        Wl_ui[1], Wr_ui[1], Wl_iu[1], Wr_iu[1], Wb, cur);

    // ---- bucketed CSR build (both graphs) ----
    k_bucket<<<2 * BBLK, 256, 0, stream>>>(ei_ui, ei_iu, cur, bkt);
    k_csr<<<2 * NBK, 256, 0, stream>>>(cur, bkt, rp_ui, re_ui, rp_iu, re_iu, csr);

    // ---- layer 0 ----
    k_agg2<<<2 * AB, 256, 0, stream>>>(xb_user, rp_ui, re_ui, mean_item,
                                       xb_item, rp_iu, re_iu, mean_user, csr);
    k_gemm2<false><<<2 * GBD, 512, 0, stream>>>(
        mean_item, xb_item, Wb + 0 * 16384, Wb + 1 * 16384,
        bl_ui[0], g_item[0], b_item[0], w_item,
        mean_user, xb_user, Wb + 2 * 16384, Wb + 3 * 16384,
        bl_iu[0], g_user[0], b_user[0], w_user);

    // ---- layer 1 ----
    k_agg2<<<2 * AB, 256, 0, stream>>>(w_user, rp_ui, re_ui, mean_item,
                                       w_item, rp_iu, re_iu, mean_user, csr);
    k_gemm2<true><<<2 * GBD, 512, 0, stream>>>(
        mean_item, w_item, Wb + 4 * 16384, Wb + 5 * 16384,
        bl_ui[1], g_item[1], b_item[1], out_item,
        mean_user, w_user, Wb + 6 * 16384, Wb + 7 * 16384,
        bl_iu[1], g_user[1], b_user[1], out_user);
}